// Round 1
// baseline (314.250 us; speedup 1.0000x reference)
//
#include <hip/hip_runtime.h>
#include <hip/hip_bf16.h>

typedef __attribute__((ext_vector_type(8))) short bf16x8;
typedef __attribute__((ext_vector_type(4))) float f32x4;
typedef unsigned short u16;

#define MFMA_BF16(a, b, c) __builtin_amdgcn_mfma_f32_16x16x32_bf16(a, b, c, 0, 0, 0)

__device__ inline u16 f2b(float x) {
  unsigned int u = __builtin_bit_cast(unsigned int, x);
  u += 0x7fffu + ((u >> 16) & 1u);
  return (u16)(u >> 16);
}

__device__ inline void gload16(void* lds, const void* g) {
  __builtin_amdgcn_global_load_lds((const __attribute__((address_space(1))) void*)g,
                                   (__attribute__((address_space(3))) void*)lds,
                                   16, 0, 0);
}

// ---------------- prep kernels ----------------

__global__ __launch_bounds__(256) void cast_f32_bf16(const float* __restrict__ src,
                                                     u16* __restrict__ dst, int n4) {
  int i = blockIdx.x * blockDim.x + threadIdx.x;
  if (i < n4) {
    float4 v = ((const float4*)src)[i];
    ushort4 o;
    o.x = f2b(v.x); o.y = f2b(v.y); o.z = f2b(v.z); o.w = f2b(v.w);
    ((ushort4*)dst)[i] = o;
  }
}

// dst[n][k] = bf16(src[k][n]); src is [K][N] f32 row-major.
__global__ __launch_bounds__(256) void transpose_cast(const float* __restrict__ src,
                                                      u16* __restrict__ dst, int K, int N) {
  __shared__ float t[32][33];
  int k0 = blockIdx.x * 32, n0 = blockIdx.y * 32;
  int tx = threadIdx.x, ty = threadIdx.y;  // 32 x 8
#pragma unroll
  for (int i = 0; i < 4; i++) t[ty + i * 8][tx] = src[(size_t)(k0 + ty + i * 8) * N + n0 + tx];
  __syncthreads();
#pragma unroll
  for (int i = 0; i < 4; i++)
    dst[(size_t)(n0 + ty + i * 8) * K + k0 + tx] = f2b(t[tx][ty + i * 8]);
}

// ---------------- GEMM (m97-style 128x128 tile, BK=32) ----------------
// A: [M][K] bf16 row-major. BT: [N][K] bf16 (i.e. B transposed). bias f32 [N].
// EPI 0: qkv split epilogue (writes Q*0.125, K, V^T as bf16). EPI 1: f32 out.
template <int EPI>
__global__ __launch_bounds__(256) void gemm_bt(
    const u16* __restrict__ A, const u16* __restrict__ BT, const float* __restrict__ bias,
    u16* __restrict__ oQ, u16* __restrict__ oK, u16* __restrict__ oVt,
    float* __restrict__ oF, int M, int N, int K, int nbx) {
  __shared__ __align__(16) u16 As[128 * 32];
  __shared__ __align__(16) u16 Bs[128 * 32];
  int tid = threadIdx.x;
  int wv = tid >> 6, lane = tid & 63, lr = lane & 15, lg = lane >> 4;
  int bx = blockIdx.x % nbx, by = blockIdx.x / nbx;
  int m0 = by * 128, n0 = bx * 128;
  int wr = (wv >> 1) * 64, wc = (wv & 1) * 64;

  f32x4 acc[4][4] = {};

  for (int k0 = 0; k0 < K; k0 += 32) {
#pragma unroll
    for (int j = 0; j < 2; j++) {
      int li = (wv * 2 + j) * 64 + lane;   // 0..511
      int row = li >> 2, kc = (li & 3) * 8;
      gload16(As + (wv * 2 + j) * 512, A + (size_t)(m0 + row) * K + k0 + kc);
      gload16(Bs + (wv * 2 + j) * 512, BT + (size_t)(n0 + row) * K + k0 + kc);
    }
    __syncthreads();
    bf16x8 a[4], b[4];
#pragma unroll
    for (int i = 0; i < 4; i++) a[i] = *(const bf16x8*)&As[(wr + i * 16 + lr) * 32 + lg * 8];
#pragma unroll
    for (int j = 0; j < 4; j++) b[j] = *(const bf16x8*)&Bs[(wc + j * 16 + lr) * 32 + lg * 8];
#pragma unroll
    for (int i = 0; i < 4; i++)
#pragma unroll
      for (int j = 0; j < 4; j++) acc[i][j] = MFMA_BF16(a[i], b[j], acc[i][j]);
    __syncthreads();
  }

#pragma unroll
  for (int i = 0; i < 4; i++) {
#pragma unroll
    for (int j = 0; j < 4; j++) {
#pragma unroll
      for (int jj = 0; jj < 4; jj++) {
        int row = m0 + wr + i * 16 + lg * 4 + jj;  // m index
        int col = n0 + wc + j * 16 + lr;           // n index
        float v = acc[i][j][jj] + bias[col];
        if (EPI == 0) {
          int bb = row >> 11, s = row & 2047;
          if (col < 1024) {
            oQ[((size_t)((bb * 16 + (col >> 6)) * 2048 + s)) * 64 + (col & 63)] = f2b(v * 0.125f);
          } else if (col < 2048) {
            int c = col - 1024;
            oK[((size_t)((bb * 16 + (c >> 6)) * 2048 + s)) * 64 + (c & 63)] = f2b(v);
          } else {
            int c = col - 2048;
            oVt[((size_t)((bb * 16 + (c >> 6)) * 64 + (c & 63))) * 2048 + s] = f2b(v);
          }
        } else {
          oF[(size_t)row * N + col] = v;
        }
      }
    }
  }
}

// ---------------- flash attention ----------------
// Q: [bh][S][64] bf16 (pre-scaled by 1/8). K: [bh][S][64] bf16. Vt: [bh][64][S] bf16.
// AO: [B*S][1024] bf16 (col = h*64+d). Head bias folded as additive ln(1.6) on key scores.
#define SEQL 2048
#define FIRST_END 682
#define SECOND_END 1365
#define LOGF16 0.47000363f

__device__ inline float head_bias(int h, int key) {
  if (h > 2) return 0.f;
  int r = (key < FIRST_END) ? 0 : (key < SECOND_END) ? 1 : 2;
  return (r == h) ? LOGF16 : 0.f;
}

__global__ __launch_bounds__(256) void attn_kernel(const u16* __restrict__ Qb,
                                                   const u16* __restrict__ Kb,
                                                   const u16* __restrict__ Vt,
                                                   u16* __restrict__ AO) {
  __shared__ __align__(16) u16 Plds[4][16 * 32];
  int tid = threadIdx.x;
  int w = tid >> 6, lane = tid & 63, lr = lane & 15, lg = lane >> 4;
  int gw = blockIdx.x * 4 + w;
  int bh = gw >> 7;
  int q0 = (gw & 127) << 4;
  int h = bh & 15, b = bh >> 4;
  u16* P = Plds[w];

  const u16* Qp = Qb + ((size_t)bh * SEQL + q0 + lr) * 64 + lg * 8;
  bf16x8 qa0 = *(const bf16x8*)(Qp);
  bf16x8 qa1 = *(const bf16x8*)(Qp + 32);

  f32x4 O[4] = {};
  float m[4], l[4];
#pragma unroll
  for (int jj = 0; jj < 4; jj++) { m[jj] = -1e30f; l[jj] = 0.f; }

  const u16* Kbase = Kb + (size_t)bh * SEQL * 64;
  const u16* Vbase = Vt + (size_t)bh * 64 * SEQL;
  int nsteps = ((q0 + 15) >> 5) + 1;

  for (int t = 0; t < nsteps; ++t) {
    int kv0 = t * 32;
    bf16x8 kb00 = *(const bf16x8*)(Kbase + (size_t)(kv0 + lr) * 64 + lg * 8);
    bf16x8 kb01 = *(const bf16x8*)(Kbase + (size_t)(kv0 + lr) * 64 + 32 + lg * 8);
    bf16x8 kb10 = *(const bf16x8*)(Kbase + (size_t)(kv0 + 16 + lr) * 64 + lg * 8);
    bf16x8 kb11 = *(const bf16x8*)(Kbase + (size_t)(kv0 + 16 + lr) * 64 + 32 + lg * 8);
    f32x4 s0 = {}, s1 = {};
    s0 = MFMA_BF16(qa0, kb00, s0);
    s0 = MFMA_BF16(qa1, kb01, s0);
    s1 = MFMA_BF16(qa0, kb10, s1);
    s1 = MFMA_BF16(qa1, kb11, s1);

    int key0 = kv0 + lr, key1 = kv0 + 16 + lr;
    float bias0 = head_bias(h, key0), bias1 = head_bias(h, key1);

#pragma unroll
    for (int jj = 0; jj < 4; jj++) {
      int q = q0 + lg * 4 + jj;
      float x0 = (key0 <= q) ? s0[jj] + bias0 : -1e30f;
      float x1 = (key1 <= q) ? s1[jj] + bias1 : -1e30f;
      float v = fmaxf(x0, x1);
      v = fmaxf(v, __shfl_xor(v, 1));
      v = fmaxf(v, __shfl_xor(v, 2));
      v = fmaxf(v, __shfl_xor(v, 4));
      v = fmaxf(v, __shfl_xor(v, 8));
      float mn = fmaxf(m[jj], v);
      float corr = __expf(m[jj] - mn);
      float p0 = __expf(x0 - mn), p1 = __expf(x1 - mn);
      float rs = p0 + p1;
      rs += __shfl_xor(rs, 1);
      rs += __shfl_xor(rs, 2);
      rs += __shfl_xor(rs, 4);
      rs += __shfl_xor(rs, 8);
      l[jj] = l[jj] * corr + rs;
      m[jj] = mn;
#pragma unroll
      for (int n = 0; n < 4; n++) O[n][jj] *= corr;
      P[(lg * 4 + jj) * 32 + lr] = f2b(p0);
      P[(lg * 4 + jj) * 32 + 16 + lr] = f2b(p1);
    }
    // LDS bounce: D-layout P -> A-layout fragment (same wave; compiler inserts lgkmcnt)
    bf16x8 pa = *(const bf16x8*)&P[lr * 32 + lg * 8];
#pragma unroll
    for (int n = 0; n < 4; n++) {
      bf16x8 vb = *(const bf16x8*)(Vbase + (size_t)(n * 16 + lr) * SEQL + kv0 + lg * 8);
      O[n] = MFMA_BF16(pa, vb, O[n]);
    }
  }

  float inv[4];
#pragma unroll
  for (int jj = 0; jj < 4; jj++) inv[jj] = 1.f / l[jj];
#pragma unroll
  for (int n = 0; n < 4; n++) {
#pragma unroll
    for (int jj = 0; jj < 4; jj++) {
      int q = q0 + lg * 4 + jj;
      AO[((size_t)(b * SEQL + q)) * 1024 + h * 64 + n * 16 + lr] = f2b(O[n][jj] * inv[jj]);
    }
  }
}

// ---------------- launch ----------------

extern "C" void kernel_launch(void* const* d_in, const int* in_sizes, int n_in,
                              void* d_out, int out_size, void* d_ws, size_t ws_size,
                              hipStream_t stream) {
  const float* hs = (const float*)d_in[0];   // [2][2048][1024]
  const float* w1 = (const float*)d_in[1];   // [1024][3072]
  const float* b1 = (const float*)d_in[2];   // [3072]
  const float* w2 = (const float*)d_in[3];   // [1024][1024]
  const float* b2 = (const float*)d_in[4];   // [1024]
  float* out = (float*)d_out;

  char* ws = (char*)d_ws;
  const size_t MB = 1u << 20;
  u16* hsb = (u16*)(ws + 0);        // 8 MB  [4096][1024] bf16
  u16* w1t = (u16*)(ws + 8 * MB);   // 6 MB  [3072][1024] bf16
  u16* w2t = (u16*)(ws + 14 * MB);  // 2 MB  [1024][1024] bf16
  u16* Qb = (u16*)(ws + 16 * MB);   // 8 MB  [32][2048][64] bf16, pre-scaled 1/8
  u16* Kb = (u16*)(ws + 24 * MB);   // 8 MB  [32][2048][64] bf16
  u16* Vt = (u16*)(ws + 32 * MB);   // 8 MB  [32][64][2048] bf16
  u16* AO = hsb;                    // reuse: [4096][1024] bf16

  cast_f32_bf16<<<4096, 256, 0, stream>>>(hs, hsb, 4096 * 1024 / 4);
  dim3 tb(32, 8);
  transpose_cast<<<dim3(32, 96), tb, 0, stream>>>(w1, w1t, 1024, 3072);
  transpose_cast<<<dim3(32, 32), tb, 0, stream>>>(w2, w2t, 1024, 1024);

  // qkv = hs @ w1 + b1  -> Q,K,V^T (bf16)
  gemm_bt<0><<<32 * 24, 256, 0, stream>>>(hsb, w1t, b1, Qb, Kb, Vt, nullptr,
                                          4096, 3072, 1024, 24);
  // flash attention with folded divergent-head bias
  attn_kernel<<<1024, 256, 0, stream>>>(Qb, Kb, Vt, AO);
  // out = AO @ w2 + b2 (f32)
  gemm_bt<1><<<32 * 8, 256, 0, stream>>>(AO, w2t, b2, nullptr, nullptr, nullptr, out,
                                         4096, 1024, 1024, 8);
}

// Round 4
// 191.725 us; speedup vs baseline: 1.6391x; 1.6391x over previous
//
#include <hip/hip_runtime.h>
#include <hip/hip_bf16.h>

typedef __attribute__((ext_vector_type(8))) short bf16x8;
typedef __attribute__((ext_vector_type(4))) float f32x4;
typedef __attribute__((ext_vector_type(16))) float f32x16;
typedef __attribute__((ext_vector_type(4))) unsigned int u32x4;
typedef unsigned short u16;

#define MFMA_BF16(a, b, c) __builtin_amdgcn_mfma_f32_16x16x32_bf16(a, b, c, 0, 0, 0)
#define MFMA32(a, b, c) __builtin_amdgcn_mfma_f32_32x32x16_bf16(a, b, c, 0, 0, 0)

__device__ inline u16 f2b(float x) {
  unsigned int u = __builtin_bit_cast(unsigned int, x);
  u += 0x7fffu + ((u >> 16) & 1u);
  return (u16)(u >> 16);
}

// exp2 via the TRANS pipe; compiler handles scheduling of the raw op.
__device__ inline float exp2_fast(float x) {
  float r;
  asm("v_exp_f32 %0, %1" : "=v"(r) : "v"(x));
  return r;
}

__device__ inline unsigned int cvtpk_bf16(float lo, float hi) {
  unsigned int r;
  asm("v_cvt_pk_bf16_f32 %0, %1, %2" : "=v"(r) : "v"(lo), "v"(hi));
  return r;
}

// v_permlane32_swap_b32 vdst, vsrc: vdst[32:63] <-> vsrc[0:31].
__device__ inline void pswap(unsigned int& dst, unsigned int& src) {
  asm("v_permlane32_swap_b32 %0, %1" : "+v"(dst), "+v"(src));
}

__device__ inline void gload16(void* lds, const void* g) {
  __builtin_amdgcn_global_load_lds((const __attribute__((address_space(1))) void*)g,
                                   (__attribute__((address_space(3))) void*)lds,
                                   16, 0, 0);
}

// ---------------- prep kernels ----------------

__global__ __launch_bounds__(256) void cast_f32_bf16(const float* __restrict__ src,
                                                     u16* __restrict__ dst, int n4) {
  int i = blockIdx.x * blockDim.x + threadIdx.x;
  if (i < n4) {
    float4 v = ((const float4*)src)[i];
    ushort4 o;
    o.x = f2b(v.x); o.y = f2b(v.y); o.z = f2b(v.z); o.w = f2b(v.w);
    ((ushort4*)dst)[i] = o;
  }
}

// dst[n][k] = bf16(src[k][n]); src is [K][N] f32 row-major.
__global__ __launch_bounds__(256) void transpose_cast(const float* __restrict__ src,
                                                      u16* __restrict__ dst, int K, int N) {
  __shared__ float t[32][33];
  int k0 = blockIdx.x * 32, n0 = blockIdx.y * 32;
  int tx = threadIdx.x, ty = threadIdx.y;  // 32 x 8
#pragma unroll
  for (int i = 0; i < 4; i++) t[ty + i * 8][tx] = src[(size_t)(k0 + ty + i * 8) * N + n0 + tx];
  __syncthreads();
#pragma unroll
  for (int i = 0; i < 4; i++)
    dst[(size_t)(n0 + ty + i * 8) * K + k0 + tx] = f2b(t[tx][ty + i * 8]);
}

// ---------------- GEMM (m97-style 128x128 tile, BK=32) ----------------
// Q is pre-scaled by log2(e)/8 so attention works in exp2 domain.
#define QSCALE 0.1803368801f

template <int EPI>
__global__ __launch_bounds__(256) void gemm_bt(
    const u16* __restrict__ A, const u16* __restrict__ BT, const float* __restrict__ bias,
    u16* __restrict__ oQ, u16* __restrict__ oK, u16* __restrict__ oVt,
    float* __restrict__ oF, int M, int N, int K, int nbx) {
  __shared__ __align__(16) u16 As[128 * 32];
  __shared__ __align__(16) u16 Bs[128 * 32];
  int tid = threadIdx.x;
  int wv = tid >> 6, lane = tid & 63, lr = lane & 15, lg = lane >> 4;
  int bx = blockIdx.x % nbx, by = blockIdx.x / nbx;
  int m0 = by * 128, n0 = bx * 128;
  int wr = (wv >> 1) * 64, wc = (wv & 1) * 64;

  f32x4 acc[4][4] = {};

  for (int k0 = 0; k0 < K; k0 += 32) {
#pragma unroll
    for (int j = 0; j < 2; j++) {
      int li = (wv * 2 + j) * 64 + lane;   // 0..511
      int row = li >> 2, kc = (li & 3) * 8;
      gload16(As + (wv * 2 + j) * 512, A + (size_t)(m0 + row) * K + k0 + kc);
      gload16(Bs + (wv * 2 + j) * 512, BT + (size_t)(n0 + row) * K + k0 + kc);
    }
    __syncthreads();
    bf16x8 a[4], b[4];
#pragma unroll
    for (int i = 0; i < 4; i++) a[i] = *(const bf16x8*)&As[(wr + i * 16 + lr) * 32 + lg * 8];
#pragma unroll
    for (int j = 0; j < 4; j++) b[j] = *(const bf16x8*)&Bs[(wc + j * 16 + lr) * 32 + lg * 8];
#pragma unroll
    for (int i = 0; i < 4; i++)
#pragma unroll
      for (int j = 0; j < 4; j++) acc[i][j] = MFMA_BF16(a[i], b[j], acc[i][j]);
    __syncthreads();
  }

#pragma unroll
  for (int i = 0; i < 4; i++) {
#pragma unroll
    for (int j = 0; j < 4; j++) {
#pragma unroll
      for (int jj = 0; jj < 4; jj++) {
        int row = m0 + wr + i * 16 + lg * 4 + jj;  // m index
        int col = n0 + wc + j * 16 + lr;           // n index
        float v = acc[i][j][jj] + bias[col];
        if (EPI == 0) {
          int bb = row >> 11, s = row & 2047;
          if (col < 1024) {
            oQ[((size_t)((bb * 16 + (col >> 6)) * 2048 + s)) * 64 + (col & 63)] = f2b(v * QSCALE);
          } else if (col < 2048) {
            int c = col - 1024;
            oK[((size_t)((bb * 16 + (c >> 6)) * 2048 + s)) * 64 + (c & 63)] = f2b(v);
          } else {
            int c = col - 2048;
            oVt[((size_t)((bb * 16 + (c >> 6)) * 64 + (c & 63))) * 2048 + s] = f2b(v);
          }
        } else {
          oF[(size_t)row * N + col] = v;
        }
      }
    }
  }
}

// ---------------- flash attention (swapped-operand 32x32 structure) ----------------
// Q: [bh][S][64] bf16 pre-scaled by log2e/8. K: [bh][S][64]. Vt: [bh][64][S].
// Scores in exp2 domain; divergent-head reweight folded as +log2(1.6) key bias.
#define SEQL 2048
#define FIRST_END 682
#define SECOND_END 1365
#define LOG2F16 0.6780719051f

__global__ __launch_bounds__(64) void attn_kernel(const u16* __restrict__ Qb,
                                                  const u16* __restrict__ Kb,
                                                  const u16* __restrict__ Vt,
                                                  u16* __restrict__ AO) {
  int l = threadIdx.x;
  int r31 = l & 31, hi = l >> 5;
  // XCD swizzle: 256 consecutive logical waves (4 bh) per XCD -> KV L2-resident.
  int w = (blockIdx.x & 7) * 256 + (blockIdx.x >> 3);
  int bh = w >> 6, tile = w & 63;
  int q0 = tile * 32;
  int h = bh & 15, b = bh >> 4;

  // Q fragments (B-operand of swapped QK): lane holds Q[q=r31][kb*16+hi*8 .. +7]
  const u16* Qp = Qb + ((size_t)bh * SEQL + q0 + r31) * 64 + hi * 8;
  bf16x8 qa[4];
#pragma unroll
  for (int kb = 0; kb < 4; kb++) qa[kb] = *(const bf16x8*)(Qp + kb * 16);

  const u16* Kp = Kb + (size_t)bh * SEQL * 64;
  const u16* Vp = Vt + (size_t)bh * 64 * SEQL;

  f32x16 o0 = {}, o1 = {};   // O^T tiles: d = dt*32 + (reg&3)+8*(reg>>2)+4*hi, q = r31
  float m = -1e30f, lsum = 0.f;

  const int nsteps = (q0 + 95) >> 6;
  const bool hasb = (h < 3);

  for (int t = 0; t < nsteps; ++t) {
    const int kv0 = t << 6;
    const bool last = (t == nsteps - 1);

    // ---- QK^T (swapped): sA/sB[reg] = S^T[key][q=r31], key = kv0(+32) + (reg&3)+8*(reg>>2)+4*hi
    bf16x8 ka[4], kb2[4];
#pragma unroll
    for (int kb = 0; kb < 4; kb++) {
      ka[kb]  = *(const bf16x8*)(Kp + (size_t)(kv0 + r31) * 64 + kb * 16 + hi * 8);
      kb2[kb] = *(const bf16x8*)(Kp + (size_t)(kv0 + 32 + r31) * 64 + kb * 16 + hi * 8);
    }
    f32x16 sA = {}, sB = {};
#pragma unroll
    for (int kb = 0; kb < 4; kb++) sA = MFMA32(ka[kb], qa[kb], sA);
#pragma unroll
    for (int kb = 0; kb < 4; kb++) sB = MFMA32(kb2[kb], qa[kb], sB);

    if (hasb) {
#pragma unroll
      for (int r = 0; r < 16; r++) {
        int kA = kv0 + ((r & 3) + 8 * (r >> 2) + 4 * hi);
        int kB = kA + 32;
        int rA = (kA < FIRST_END) ? 0 : (kA < SECOND_END) ? 1 : 2;
        int rB = (kB < FIRST_END) ? 0 : (kB < SECOND_END) ? 1 : 2;
        if (rA == h) sA[r] += LOG2F16;
        if (rB == h) sB[r] += LOG2F16;
      }
    }
    if (last) {
      int q = q0 + r31;
#pragma unroll
      for (int r = 0; r < 16; r++) {
        int kA = kv0 + ((r & 3) + 8 * (r >> 2) + 4 * hi);
        if (kA > q) sA[r] = -1e30f;
        if (kA + 32 > q) sB[r] = -1e30f;
      }
    }

    // ---- online softmax (lane-local row, one cross-lane exchange)
#define MAX4(v, i) fmaxf(fmaxf(v[i], v[i + 1]), fmaxf(v[i + 2], v[i + 3]))
    float mA = fmaxf(fmaxf(MAX4(sA, 0), MAX4(sA, 4)), fmaxf(MAX4(sA, 8), MAX4(sA, 12)));
    float mB = fmaxf(fmaxf(MAX4(sB, 0), MAX4(sB, 4)), fmaxf(MAX4(sB, 8), MAX4(sB, 12)));
    float mx = fmaxf(mA, mB);
    mx = fmaxf(mx, __shfl_xor(mx, 32));
    float mn = fmaxf(m, mx);
    float corr = exp2_fast(m - mn);
    m = mn;

    unsigned int wA[8], wB[8];
    float s0 = 0.f, s1 = 0.f;
#pragma unroll
    for (int i = 0; i < 8; i++) {
      float pa0 = exp2_fast(sA[2 * i] - mn), pa1 = exp2_fast(sA[2 * i + 1] - mn);
      float pb0 = exp2_fast(sB[2 * i] - mn), pb1 = exp2_fast(sB[2 * i + 1] - mn);
      s0 += pa0 + pa1;
      s1 += pb0 + pb1;
      wA[i] = cvtpk_bf16(pa0, pa1);
      wB[i] = cvtpk_bf16(pb0, pb1);
    }
    float ssum = s0 + s1;
    ssum += __shfl_xor(ssum, 32);
    lsum = lsum * corr + ssum;
    o0 *= corr;
    o1 *= corr;

    // ---- P^T B-fragments via permlane32_swap.
    // pswap(w0,w2): w0 <- {hi0: keys(0,1)+c16, hi1: keys(8,9)+c16}  (B-frag word0)
    //               w2 <- {hi0: keys(4,5)+c16, hi1: keys(12,13)+c16} (B-frag word2)
    pswap(wA[0], wA[2]); pswap(wA[1], wA[3]);
    pswap(wA[4], wA[6]); pswap(wA[5], wA[7]);
    pswap(wB[0], wB[2]); pswap(wB[1], wB[3]);
    pswap(wB[4], wB[6]); pswap(wB[5], wB[7]);

    bf16x8 pb[4];
    pb[0] = __builtin_bit_cast(bf16x8, (u32x4){wA[0], wA[1], wA[2], wA[3]});
    pb[1] = __builtin_bit_cast(bf16x8, (u32x4){wA[4], wA[5], wA[6], wA[7]});
    pb[2] = __builtin_bit_cast(bf16x8, (u32x4){wB[0], wB[1], wB[2], wB[3]});
    pb[3] = __builtin_bit_cast(bf16x8, (u32x4){wB[4], wB[5], wB[6], wB[7]});

    // ---- PV (swapped): O^T += V^T * P^T, key-chunks of 16
#pragma unroll
    for (int c = 0; c < 4; c++) {
      bf16x8 va0 = *(const bf16x8*)(Vp + (size_t)r31 * SEQL + kv0 + c * 16 + hi * 8);
      bf16x8 va1 = *(const bf16x8*)(Vp + (size_t)(r31 + 32) * SEQL + kv0 + c * 16 + hi * 8);
      o0 = MFMA32(va0, pb[c], o0);
      o1 = MFMA32(va1, pb[c], o1);
    }
  }

  // ---- epilogue: lane q = q0 + r31 writes its 64 d-values
  float inv = 1.0f / lsum;
  u16* aop = AO + ((size_t)(b * SEQL + q0 + r31)) * 1024 + h * 64;
#pragma unroll
  for (int dt = 0; dt < 2; dt++) {
    const f32x16& o = dt ? o1 : o0;
#pragma unroll
    for (int r = 0; r < 16; r += 2) {
      int d = dt * 32 + (r & 3) + 8 * (r >> 2) + 4 * hi;
      unsigned int wo = (unsigned int)f2b(o[r] * inv) | ((unsigned int)f2b(o[r + 1] * inv) << 16);
      *(unsigned int*)(aop + d) = wo;
    }
  }
}

// ---------------- launch ----------------

extern "C" void kernel_launch(void* const* d_in, const int* in_sizes, int n_in,
                              void* d_out, int out_size, void* d_ws, size_t ws_size,
                              hipStream_t stream) {
  const float* hs = (const float*)d_in[0];   // [2][2048][1024]
  const float* w1 = (const float*)d_in[1];   // [1024][3072]
  const float* b1 = (const float*)d_in[2];   // [3072]
  const float* w2 = (const float*)d_in[3];   // [1024][1024]
  const float* b2 = (const float*)d_in[4];   // [1024]
  float* out = (float*)d_out;

  char* ws = (char*)d_ws;
  const size_t MB = 1u << 20;
  u16* hsb = (u16*)(ws + 0);        // 8 MB  [4096][1024] bf16
  u16* w1t = (u16*)(ws + 8 * MB);   // 6 MB  [3072][1024] bf16
  u16* w2t = (u16*)(ws + 14 * MB);  // 2 MB  [1024][1024] bf16
  u16* Qb = (u16*)(ws + 16 * MB);   // 8 MB  [32][2048][64] bf16, pre-scaled log2e/8
  u16* Kb = (u16*)(ws + 24 * MB);   // 8 MB  [32][2048][64] bf16
  u16* Vt = (u16*)(ws + 32 * MB);   // 8 MB  [32][64][2048] bf16
  u16* AO = hsb;                    // reuse: [4096][1024] bf16

  cast_f32_bf16<<<4096, 256, 0, stream>>>(hs, hsb, 4096 * 1024 / 4);
  dim3 tb(32, 8);
  transpose_cast<<<dim3(32, 96), tb, 0, stream>>>(w1, w1t, 1024, 3072);
  transpose_cast<<<dim3(32, 32), tb, 0, stream>>>(w2, w2t, 1024, 1024);

  // qkv = hs @ w1 + b1  -> Q,K,V^T (bf16)
  gemm_bt<0><<<32 * 24, 256, 0, stream>>>(hsb, w1t, b1, Qb, Kb, Vt, nullptr,
                                          4096, 3072, 1024, 24);
  // flash attention, swapped-operand 32x32 MFMA, 1 wave / 32 q-rows
  attn_kernel<<<2048, 64, 0, stream>>>(Qb, Kb, Vt, AO);
  // out = AO @ w2 + b2 (f32)
  gemm_bt<1><<<32 * 8, 256, 0, stream>>>(AO, w2t, b2, nullptr, nullptr, nullptr, out,
                                         4096, 1024, 1024, 8);
}

// Round 5
// 180.299 us; speedup vs baseline: 1.7429x; 1.0634x over previous
//
#include <hip/hip_runtime.h>
#include <hip/hip_bf16.h>

typedef __attribute__((ext_vector_type(8))) short bf16x8;
typedef __attribute__((ext_vector_type(4))) float f32x4;
typedef __attribute__((ext_vector_type(16))) float f32x16;
typedef __attribute__((ext_vector_type(4))) unsigned int u32x4;
typedef unsigned short u16;

#define MFMA_BF16(a, b, c) __builtin_amdgcn_mfma_f32_16x16x32_bf16(a, b, c, 0, 0, 0)
#define MFMA32(a, b, c) __builtin_amdgcn_mfma_f32_32x32x16_bf16(a, b, c, 0, 0, 0)

__device__ inline u16 f2b(float x) {
  unsigned int u = __builtin_bit_cast(unsigned int, x);
  u += 0x7fffu + ((u >> 16) & 1u);
  return (u16)(u >> 16);
}

__device__ inline float exp2_fast(float x) {
  float r;
  asm("v_exp_f32 %0, %1" : "=v"(r) : "v"(x));
  return r;
}

__device__ inline unsigned int cvtpk_bf16(float lo, float hi) {
  unsigned int r;
  asm("v_cvt_pk_bf16_f32 %0, %1, %2" : "=v"(r) : "v"(lo), "v"(hi));
  return r;
}

// v_permlane32_swap_b32 vdst, vsrc: vdst[32:63] <-> vsrc[0:31].
__device__ inline void pswap(unsigned int& dst, unsigned int& src) {
  asm("v_permlane32_swap_b32 %0, %1" : "+v"(dst), "+v"(src));
}

__device__ inline void gload16(void* lds, const void* g) {
  __builtin_amdgcn_global_load_lds((const __attribute__((address_space(1))) void*)g,
                                   (__attribute__((address_space(3))) void*)lds,
                                   16, 0, 0);
}

// ---------------- prep kernels ----------------

__global__ __launch_bounds__(256) void cast_f32_bf16(const float* __restrict__ src,
                                                     u16* __restrict__ dst, int n4) {
  int i = blockIdx.x * blockDim.x + threadIdx.x;
  if (i < n4) {
    float4 v = ((const float4*)src)[i];
    ushort4 o;
    o.x = f2b(v.x); o.y = f2b(v.y); o.z = f2b(v.z); o.w = f2b(v.w);
    ((ushort4*)dst)[i] = o;
  }
}

// dst[n][k] = bf16(src[k][n]); src is [K][N] f32 row-major.
__global__ __launch_bounds__(256) void transpose_cast(const float* __restrict__ src,
                                                      u16* __restrict__ dst, int K, int N) {
  __shared__ float t[32][33];
  int k0 = blockIdx.x * 32, n0 = blockIdx.y * 32;
  int tx = threadIdx.x, ty = threadIdx.y;  // 32 x 8
#pragma unroll
  for (int i = 0; i < 4; i++) t[ty + i * 8][tx] = src[(size_t)(k0 + ty + i * 8) * N + n0 + tx];
  __syncthreads();
#pragma unroll
  for (int i = 0; i < 4; i++)
    dst[(size_t)(n0 + ty + i * 8) * K + k0 + tx] = f2b(t[tx][ty + i * 8]);
}

// ---------------- GEMM (m97-style 128x128 tile, BK=32) ----------------
// Q is pre-scaled by log2(e)/8 so attention works in exp2 domain.
#define QSCALE 0.1803368801f

template <int EPI>
__global__ __launch_bounds__(256) void gemm_bt(
    const u16* __restrict__ A, const u16* __restrict__ BT, const float* __restrict__ bias,
    u16* __restrict__ oQ, u16* __restrict__ oK, u16* __restrict__ oVt,
    float* __restrict__ oF, int M, int N, int K, int nbx) {
  __shared__ __align__(16) u16 As[128 * 32];
  __shared__ __align__(16) u16 Bs[128 * 32];
  int tid = threadIdx.x;
  int wv = tid >> 6, lane = tid & 63, lr = lane & 15, lg = lane >> 4;
  int bx = blockIdx.x % nbx, by = blockIdx.x / nbx;
  int m0 = by * 128, n0 = bx * 128;
  int wr = (wv >> 1) * 64, wc = (wv & 1) * 64;

  f32x4 acc[4][4] = {};

  for (int k0 = 0; k0 < K; k0 += 32) {
#pragma unroll
    for (int j = 0; j < 2; j++) {
      int li = (wv * 2 + j) * 64 + lane;   // 0..511
      int row = li >> 2, kc = (li & 3) * 8;
      gload16(As + (wv * 2 + j) * 512, A + (size_t)(m0 + row) * K + k0 + kc);
      gload16(Bs + (wv * 2 + j) * 512, BT + (size_t)(n0 + row) * K + k0 + kc);
    }
    __syncthreads();
    bf16x8 a[4], b[4];
#pragma unroll
    for (int i = 0; i < 4; i++) a[i] = *(const bf16x8*)&As[(wr + i * 16 + lr) * 32 + lg * 8];
#pragma unroll
    for (int j = 0; j < 4; j++) b[j] = *(const bf16x8*)&Bs[(wc + j * 16 + lr) * 32 + lg * 8];
#pragma unroll
    for (int i = 0; i < 4; i++)
#pragma unroll
      for (int j = 0; j < 4; j++) acc[i][j] = MFMA_BF16(a[i], b[j], acc[i][j]);
    __syncthreads();
  }

#pragma unroll
  for (int i = 0; i < 4; i++) {
#pragma unroll
    for (int j = 0; j < 4; j++) {
#pragma unroll
      for (int jj = 0; jj < 4; jj++) {
        int row = m0 + wr + i * 16 + lg * 4 + jj;  // m index
        int col = n0 + wc + j * 16 + lr;           // n index
        float v = acc[i][j][jj] + bias[col];
        if (EPI == 0) {
          int bb = row >> 11, s = row & 2047;
          if (col < 1024) {
            oQ[((size_t)((bb * 16 + (col >> 6)) * 2048 + s)) * 64 + (col & 63)] = f2b(v * QSCALE);
          } else if (col < 2048) {
            int c = col - 1024;
            oK[((size_t)((bb * 16 + (c >> 6)) * 2048 + s)) * 64 + (c & 63)] = f2b(v);
          } else {
            int c = col - 2048;
            oVt[((size_t)((bb * 16 + (c >> 6)) * 64 + (c & 63))) * 2048 + s] = f2b(v);
          }
        } else {
          oF[(size_t)row * N + col] = v;
        }
      }
    }
  }
}

// ---------------- flash attention (swapped 32x32, LDS-staged KV) ----------------
// Q: [bh][S][64] bf16 pre-scaled by log2e/8. K: [bh][S][64]. Vt: [bh][64][S].
// Block = 4 waves = 4 consecutive 32-row q-tiles of one bh; per 64-key step the
// block stages K-tile [64][64] and V^T-tile [64][64] into LDS (pre-swizzled
// global source + linear LDS dest, XOR-swizzled reads; rule #21 / T2).
#define SEQL 2048
#define FIRST_END 682
#define SECOND_END 1365
#define LOG2F16 0.6780719051f

__global__ __launch_bounds__(256) void attn_kernel(const u16* __restrict__ Qb,
                                                   const u16* __restrict__ Kb,
                                                   const u16* __restrict__ Vt,
                                                   u16* __restrict__ AO) {
  __shared__ __align__(16) u16 Kl[2][4096];
  __shared__ __align__(16) u16 Vl[2][4096];

  int tid = threadIdx.x;
  int w = tid >> 6, l = tid & 63;
  int r31 = l & 31, hi = l >> 5;

  // XCD mapping: block b -> XCD b&7 (round-robin); give each XCD 4 bh.
  int xcd = blockIdx.x & 7, slot = blockIdx.x >> 3;   // slot 0..63
  int bh = xcd * 4 + (slot >> 4);
  int qb = slot & 15;
  int q0B = qb * 128;
  int q0 = q0B + w * 32;
  int h = bh & 15, b = bh >> 4;

  // Q fragments (B-operand of swapped QK): lane holds Q[q=r31][kb*16+hi*8 .. +7]
  const u16* Qp = Qb + ((size_t)bh * SEQL + q0 + r31) * 64 + hi * 8;
  bf16x8 qa[4];
#pragma unroll
  for (int kb = 0; kb < 4; kb++) qa[kb] = *(const bf16x8*)(Qp + kb * 16);

  const char* Ktb = (const char*)(Kb + (size_t)bh * SEQL * 64);
  const char* Vtb = (const char*)(Vt + (size_t)bh * 64 * SEQL);

  f32x16 o0 = {}, o1 = {};   // O^T tiles: d = dt*32 + (reg&3)+8*(reg>>2)+4*hi, q = r31
  float m = -1e30f, lsum = 0.f;

  const int nsteps_w = (q0 + 95) >> 6;          // this wave's useful steps
  const int nsteps_blk = (q0B + 191) >> 6;      // block loop count (wave 3's)
  const bool hasb = (h < 3);
  const int swa = (r31 & 7) << 4;               // read-side XOR swizzle

  // ---- staging helper (lambda): K tile contiguous 8KB; V rows stride 4KB.
  auto stage = [&](int buf, int kv0) {
#pragma unroll
    for (int p = 0; p < 2; p++) {
      int o = p * 4096 + w * 1024 + l * 16;     // linear LDS byte offset
      int row = o >> 7;
      int os = o ^ ((row & 7) << 4);            // pre-swizzled source position
      gload16((char*)&Kl[buf][0] + p * 4096 + w * 1024,
              Ktb + (size_t)kv0 * 128 + os);
      gload16((char*)&Vl[buf][0] + p * 4096 + w * 1024,
              Vtb + (size_t)row * 4096 + (size_t)kv0 * 2 + (os & 127));
    }
  };

  stage(0, 0);
  __syncthreads();

  for (int t = 0; t < nsteps_blk; ++t) {
    const int cur = t & 1;
    if (t + 1 < nsteps_blk) stage(cur ^ 1, (t + 1) << 6);

    if (t < nsteps_w) {
      const int kv0 = t << 6;
      const bool last = (t == nsteps_w - 1);
      const char* Kbuf = (const char*)&Kl[cur][0];
      const char* Vbuf = (const char*)&Vl[cur][0];

      // ---- QK^T (swapped): sA/sB[reg] = S^T[key][q=r31]
      bf16x8 ka[4], kb2[4];
#pragma unroll
      for (int kb = 0; kb < 4; kb++) {
        int col = kb * 32 + hi * 16;
        ka[kb]  = *(const bf16x8*)(Kbuf + r31 * 128 + (col ^ swa));
        kb2[kb] = *(const bf16x8*)(Kbuf + (r31 + 32) * 128 + (col ^ swa));
      }
      f32x16 sA = {}, sB = {};
#pragma unroll
      for (int kb = 0; kb < 4; kb++) sA = MFMA32(ka[kb], qa[kb], sA);
#pragma unroll
      for (int kb = 0; kb < 4; kb++) sB = MFMA32(kb2[kb], qa[kb], sB);

      if (hasb) {
#pragma unroll
        for (int r = 0; r < 16; r++) {
          int kA = kv0 + ((r & 3) + 8 * (r >> 2) + 4 * hi);
          int kB = kA + 32;
          int rA = (kA < FIRST_END) ? 0 : (kA < SECOND_END) ? 1 : 2;
          int rB = (kB < FIRST_END) ? 0 : (kB < SECOND_END) ? 1 : 2;
          if (rA == h) sA[r] += LOG2F16;
          if (rB == h) sB[r] += LOG2F16;
        }
      }
      if (last) {
        int q = q0 + r31;
#pragma unroll
        for (int r = 0; r < 16; r++) {
          int kA = kv0 + ((r & 3) + 8 * (r >> 2) + 4 * hi);
          if (kA > q) sA[r] = -1e30f;
          if (kA + 32 > q) sB[r] = -1e30f;
        }
      }

      // ---- online softmax (lane-local row, one cross-lane exchange)
#define MAX4(v, i) fmaxf(fmaxf(v[i], v[i + 1]), fmaxf(v[i + 2], v[i + 3]))
      float mA = fmaxf(fmaxf(MAX4(sA, 0), MAX4(sA, 4)), fmaxf(MAX4(sA, 8), MAX4(sA, 12)));
      float mB = fmaxf(fmaxf(MAX4(sB, 0), MAX4(sB, 4)), fmaxf(MAX4(sB, 8), MAX4(sB, 12)));
      float mx = fmaxf(mA, mB);
      mx = fmaxf(mx, __shfl_xor(mx, 32));
      float mn = fmaxf(m, mx);
      float corr = exp2_fast(m - mn);
      m = mn;

      unsigned int wA[8], wB[8];
      float s0 = 0.f, s1 = 0.f;
#pragma unroll
      for (int i = 0; i < 8; i++) {
        float pa0 = exp2_fast(sA[2 * i] - mn), pa1 = exp2_fast(sA[2 * i + 1] - mn);
        float pb0 = exp2_fast(sB[2 * i] - mn), pb1 = exp2_fast(sB[2 * i + 1] - mn);
        s0 += pa0 + pa1;
        s1 += pb0 + pb1;
        wA[i] = cvtpk_bf16(pa0, pa1);
        wB[i] = cvtpk_bf16(pb0, pb1);
      }
      float ssum = s0 + s1;
      ssum += __shfl_xor(ssum, 32);
      lsum = lsum * corr + ssum;
      o0 *= corr;
      o1 *= corr;

      // ---- P^T B-fragments via permlane32_swap
      pswap(wA[0], wA[2]); pswap(wA[1], wA[3]);
      pswap(wA[4], wA[6]); pswap(wA[5], wA[7]);
      pswap(wB[0], wB[2]); pswap(wB[1], wB[3]);
      pswap(wB[4], wB[6]); pswap(wB[5], wB[7]);

      bf16x8 pb[4];
      pb[0] = __builtin_bit_cast(bf16x8, (u32x4){wA[0], wA[1], wA[2], wA[3]});
      pb[1] = __builtin_bit_cast(bf16x8, (u32x4){wA[4], wA[5], wA[6], wA[7]});
      pb[2] = __builtin_bit_cast(bf16x8, (u32x4){wB[0], wB[1], wB[2], wB[3]});
      pb[3] = __builtin_bit_cast(bf16x8, (u32x4){wB[4], wB[5], wB[6], wB[7]});

      // ---- PV (swapped): O^T += V^T * P^T, key-chunks of 16
#pragma unroll
      for (int c = 0; c < 4; c++) {
        int col = c * 32 + hi * 16;
        bf16x8 va0 = *(const bf16x8*)(Vbuf + r31 * 128 + (col ^ swa));
        bf16x8 va1 = *(const bf16x8*)(Vbuf + (r31 + 32) * 128 + (col ^ swa));
        o0 = MFMA32(va0, pb[c], o0);
        o1 = MFMA32(va1, pb[c], o1);
      }
    }
    __syncthreads();
  }

  // ---- epilogue: lane q = q0 + r31 writes its 64 d-values
  float inv = 1.0f / lsum;
  u16* aop = AO + ((size_t)(b * SEQL + q0 + r31)) * 1024 + h * 64;
#pragma unroll
  for (int dt = 0; dt < 2; dt++) {
    const f32x16& o = dt ? o1 : o0;
#pragma unroll
    for (int r = 0; r < 16; r += 2) {
      int d = dt * 32 + (r & 3) + 8 * (r >> 2) + 4 * hi;
      unsigned int wo = (unsigned int)f2b(o[r] * inv) | ((unsigned int)f2b(o[r + 1] * inv) << 16);
      *(unsigned int*)(aop + d) = wo;
    }
  }
}

// ---------------- launch ----------------

extern "C" void kernel_launch(void* const* d_in, const int* in_sizes, int n_in,
                              void* d_out, int out_size, void* d_ws, size_t ws_size,
                              hipStream_t stream) {
  const float* hs = (const float*)d_in[0];   // [2][2048][1024]
  const float* w1 = (const float*)d_in[1];   // [1024][3072]
  const float* b1 = (const float*)d_in[2];   // [3072]
  const float* w2 = (const float*)d_in[3];   // [1024][1024]
  const float* b2 = (const float*)d_in[4];   // [1024]
  float* out = (float*)d_out;

  char* ws = (char*)d_ws;
  const size_t MB = 1u << 20;
  u16* hsb = (u16*)(ws + 0);        // 8 MB  [4096][1024] bf16
  u16* w1t = (u16*)(ws + 8 * MB);   // 6 MB  [3072][1024] bf16
  u16* w2t = (u16*)(ws + 14 * MB);  // 2 MB  [1024][1024] bf16
  u16* Qb = (u16*)(ws + 16 * MB);   // 8 MB  [32][2048][64] bf16, pre-scaled log2e/8
  u16* Kb = (u16*)(ws + 24 * MB);   // 8 MB  [32][2048][64] bf16
  u16* Vt = (u16*)(ws + 32 * MB);   // 8 MB  [32][64][2048] bf16
  u16* AO = hsb;                    // reuse: [4096][1024] bf16

  cast_f32_bf16<<<4096, 256, 0, stream>>>(hs, hsb, 4096 * 1024 / 4);
  dim3 tb(32, 8);
  transpose_cast<<<dim3(32, 96), tb, 0, stream>>>(w1, w1t, 1024, 3072);
  transpose_cast<<<dim3(32, 32), tb, 0, stream>>>(w2, w2t, 1024, 1024);

  // qkv = hs @ w1 + b1  -> Q,K,V^T (bf16)
  gemm_bt<0><<<32 * 24, 256, 0, stream>>>(hsb, w1t, b1, Qb, Kb, Vt, nullptr,
                                          4096, 3072, 1024, 24);
  // flash attention: 512 blocks x 4 waves, LDS-staged KV
  attn_kernel<<<512, 256, 0, stream>>>(Qb, Kb, Vt, AO);
  // out = AO @ w2 + b2 (f32)
  gemm_bt<1><<<32 * 8, 256, 0, stream>>>(AO, w2t, b2, nullptr, nullptr, nullptr, out,
                                         4096, 1024, 1024, 8);
}

// Round 6
// 163.757 us; speedup vs baseline: 1.9190x; 1.1010x over previous
//
#include <hip/hip_runtime.h>
#include <hip/hip_bf16.h>

typedef __attribute__((ext_vector_type(8))) short bf16x8;
typedef __attribute__((ext_vector_type(4))) float f32x4;
typedef __attribute__((ext_vector_type(16))) float f32x16;
typedef __attribute__((ext_vector_type(4))) unsigned int u32x4;
typedef unsigned short u16;

#define MFMA_BF16(a, b, c) __builtin_amdgcn_mfma_f32_16x16x32_bf16(a, b, c, 0, 0, 0)
#define MFMA32(a, b, c) __builtin_amdgcn_mfma_f32_32x32x16_bf16(a, b, c, 0, 0, 0)

__device__ inline u16 f2b(float x) {
  unsigned int u = __builtin_bit_cast(unsigned int, x);
  u += 0x7fffu + ((u >> 16) & 1u);
  return (u16)(u >> 16);
}

__device__ inline float exp2_fast(float x) {
  float r;
  asm("v_exp_f32 %0, %1" : "=v"(r) : "v"(x));
  return r;
}

__device__ inline unsigned int cvtpk_bf16(float lo, float hi) {
  unsigned int r;
  asm("v_cvt_pk_bf16_f32 %0, %1, %2" : "=v"(r) : "v"(lo), "v"(hi));
  return r;
}

// v_permlane32_swap_b32 vdst, vsrc: vdst[32:63] <-> vsrc[0:31].
__device__ inline void pswap(unsigned int& dst, unsigned int& src) {
  asm("v_permlane32_swap_b32 %0, %1" : "+v"(dst), "+v"(src));
}

__device__ inline void gload16(void* lds, const void* g) {
  __builtin_amdgcn_global_load_lds((const __attribute__((address_space(1))) void*)g,
                                   (__attribute__((address_space(3))) void*)lds,
                                   16, 0, 0);
}

// ---------------- prep kernels ----------------

__global__ __launch_bounds__(256) void cast_f32_bf16(const float* __restrict__ src,
                                                     u16* __restrict__ dst, int n4) {
  int i = blockIdx.x * blockDim.x + threadIdx.x;
  if (i < n4) {
    float4 v = ((const float4*)src)[i];
    ushort4 o;
    o.x = f2b(v.x); o.y = f2b(v.y); o.z = f2b(v.z); o.w = f2b(v.w);
    ((ushort4*)dst)[i] = o;
  }
}

// dst[n][k] = bf16(src[k][n]); src is [K][N] f32 row-major.
__global__ __launch_bounds__(256) void transpose_cast(const float* __restrict__ src,
                                                      u16* __restrict__ dst, int K, int N) {
  __shared__ float t[32][33];
  int k0 = blockIdx.x * 32, n0 = blockIdx.y * 32;
  int tx = threadIdx.x, ty = threadIdx.y;  // 32 x 8
#pragma unroll
  for (int i = 0; i < 4; i++) t[ty + i * 8][tx] = src[(size_t)(k0 + ty + i * 8) * N + n0 + tx];
  __syncthreads();
#pragma unroll
  for (int i = 0; i < 4; i++)
    dst[(size_t)(n0 + ty + i * 8) * K + k0 + tx] = f2b(t[tx][ty + i * 8]);
}

// ---------------- GEMM (m97-style 128x128 tile, BK=32) ----------------
// Q is pre-scaled by log2(e)/8 so attention works in exp2 domain.
#define QSCALE 0.1803368801f

template <int EPI>
__global__ __launch_bounds__(256) void gemm_bt(
    const u16* __restrict__ A, const u16* __restrict__ BT, const float* __restrict__ bias,
    u16* __restrict__ oQ, u16* __restrict__ oK, u16* __restrict__ oVt,
    float* __restrict__ oF, int M, int N, int K, int nbx) {
  __shared__ __align__(16) u16 As[128 * 32];
  __shared__ __align__(16) u16 Bs[128 * 32];
  int tid = threadIdx.x;
  int wv = tid >> 6, lane = tid & 63, lr = lane & 15, lg = lane >> 4;
  int bx = blockIdx.x % nbx, by = blockIdx.x / nbx;
  int m0 = by * 128, n0 = bx * 128;
  int wr = (wv >> 1) * 64, wc = (wv & 1) * 64;

  f32x4 acc[4][4] = {};

  for (int k0 = 0; k0 < K; k0 += 32) {
#pragma unroll
    for (int j = 0; j < 2; j++) {
      int li = (wv * 2 + j) * 64 + lane;   // 0..511
      int row = li >> 2, kc = (li & 3) * 8;
      gload16(As + (wv * 2 + j) * 512, A + (size_t)(m0 + row) * K + k0 + kc);
      gload16(Bs + (wv * 2 + j) * 512, BT + (size_t)(n0 + row) * K + k0 + kc);
    }
    __syncthreads();
    bf16x8 a[4], b[4];
#pragma unroll
    for (int i = 0; i < 4; i++) a[i] = *(const bf16x8*)&As[(wr + i * 16 + lr) * 32 + lg * 8];
#pragma unroll
    for (int j = 0; j < 4; j++) b[j] = *(const bf16x8*)&Bs[(wc + j * 16 + lr) * 32 + lg * 8];
#pragma unroll
    for (int i = 0; i < 4; i++)
#pragma unroll
      for (int j = 0; j < 4; j++) acc[i][j] = MFMA_BF16(a[i], b[j], acc[i][j]);
    __syncthreads();
  }

#pragma unroll
  for (int i = 0; i < 4; i++) {
#pragma unroll
    for (int j = 0; j < 4; j++) {
#pragma unroll
      for (int jj = 0; jj < 4; jj++) {
        int row = m0 + wr + i * 16 + lg * 4 + jj;  // m index
        int col = n0 + wc + j * 16 + lr;           // n index
        float v = acc[i][j][jj] + bias[col];
        if (EPI == 0) {
          int bb = row >> 11, s = row & 2047;
          if (col < 1024) {
            oQ[((size_t)((bb * 16 + (col >> 6)) * 2048 + s)) * 64 + (col & 63)] = f2b(v * QSCALE);
          } else if (col < 2048) {
            int c = col - 1024;
            oK[((size_t)((bb * 16 + (c >> 6)) * 2048 + s)) * 64 + (c & 63)] = f2b(v);
          } else {
            int c = col - 2048;
            oVt[((size_t)((bb * 16 + (c >> 6)) * 64 + (c & 63))) * 2048 + s] = f2b(v);
          }
        } else {
          oF[(size_t)row * N + col] = v;
        }
      }
    }
  }
}

// ---------------- flash attention (swapped 32x32, KV-split across 4 waves) ----------------
// Q: [bh][S][64] bf16 pre-scaled by log2e/8. K: [bh][S][64]. Vt: [bh][64][S].
// One 32-row q-tile per BLOCK; the 4 waves split the causal KV range by
// stride-4 step interleave, each with independent online softmax; partials
// (m, l, O) merged through LDS at the end.
#define SEQL 2048
#define FIRST_END 682
#define SECOND_END 1365
#define LOG2F16 0.6780719051f

__global__ __launch_bounds__(256) void attn_kernel(const u16* __restrict__ Qb,
                                                   const u16* __restrict__ Kb,
                                                   const u16* __restrict__ Vt,
                                                   u16* __restrict__ AO) {
  __shared__ float Ol[4][32][66];   // [wave][reg r][lane], padded for bank spread
  __shared__ float Ml[4][32], Ll[4][32], Cl[4][32];

  int tid = threadIdx.x;
  int w = tid >> 6, l = tid & 63;
  int r31 = l & 31, hi = l >> 5;

  // 2048 blocks: XCD gets 4 bh x 64 tiles; big tiles (qt=63) launch first.
  int xcd = blockIdx.x & 7, slot = blockIdx.x >> 3;   // slot 0..255
  int bh = xcd * 4 + (slot >> 6);
  int qt = 63 - (slot & 63);
  int q0 = qt * 32;
  int h = bh & 15, b = bh >> 4;

  // Q fragments (B-operand of swapped QK): lane holds Q[q=r31][kb*16+hi*8 .. +7]
  const u16* Qp = Qb + ((size_t)bh * SEQL + q0 + r31) * 64 + hi * 8;
  bf16x8 qa[4];
#pragma unroll
  for (int kb = 0; kb < 4; kb++) qa[kb] = *(const bf16x8*)(Qp + kb * 16);

  const u16* Kp = Kb + (size_t)bh * SEQL * 64;
  const u16* Vp = Vt + (size_t)bh * 64 * SEQL;

  f32x16 o0 = {}, o1 = {};   // O^T tiles: d = dt*32 + (reg&3)+8*(reg>>2)+4*hi, q = r31
  float m = -1e30f, lsum = 0.f;

  const int N = (q0 + 95) >> 6;   // total 64-key steps for this q-tile
  const bool hasb = (h < 3);

  for (int t = w; t < N; t += 4) {
    const int kv0 = t << 6;
    const bool last = (t == N - 1);

    // ---- QK^T (swapped): sA/sB[reg] = S^T[key][q=r31]
    bf16x8 ka[4], kb2[4];
#pragma unroll
    for (int kb = 0; kb < 4; kb++) {
      ka[kb]  = *(const bf16x8*)(Kp + (size_t)(kv0 + r31) * 64 + kb * 16 + hi * 8);
      kb2[kb] = *(const bf16x8*)(Kp + (size_t)(kv0 + 32 + r31) * 64 + kb * 16 + hi * 8);
    }
    f32x16 sA = {}, sB = {};
#pragma unroll
    for (int kb = 0; kb < 4; kb++) sA = MFMA32(ka[kb], qa[kb], sA);
#pragma unroll
    for (int kb = 0; kb < 4; kb++) sB = MFMA32(kb2[kb], qa[kb], sB);

    if (hasb) {
#pragma unroll
      for (int r = 0; r < 16; r++) {
        int kA = kv0 + ((r & 3) + 8 * (r >> 2) + 4 * hi);
        int kB = kA + 32;
        int rA = (kA < FIRST_END) ? 0 : (kA < SECOND_END) ? 1 : 2;
        int rB = (kB < FIRST_END) ? 0 : (kB < SECOND_END) ? 1 : 2;
        if (rA == h) sA[r] += LOG2F16;
        if (rB == h) sB[r] += LOG2F16;
      }
    }
    if (last) {
      int q = q0 + r31;
#pragma unroll
      for (int r = 0; r < 16; r++) {
        int kA = kv0 + ((r & 3) + 8 * (r >> 2) + 4 * hi);
        if (kA > q) sA[r] = -1e30f;
        if (kA + 32 > q) sB[r] = -1e30f;
      }
    }

    // ---- online softmax (lane-local row, one cross-lane exchange)
#define MAX4(v, i) fmaxf(fmaxf(v[i], v[i + 1]), fmaxf(v[i + 2], v[i + 3]))
    float mA = fmaxf(fmaxf(MAX4(sA, 0), MAX4(sA, 4)), fmaxf(MAX4(sA, 8), MAX4(sA, 12)));
    float mB = fmaxf(fmaxf(MAX4(sB, 0), MAX4(sB, 4)), fmaxf(MAX4(sB, 8), MAX4(sB, 12)));
    float mx = fmaxf(mA, mB);
    mx = fmaxf(mx, __shfl_xor(mx, 32));
    float mn = fmaxf(m, mx);
    float corr = exp2_fast(m - mn);
    m = mn;

    unsigned int wA[8], wB[8];
    float s0 = 0.f, s1 = 0.f;
#pragma unroll
    for (int i = 0; i < 8; i++) {
      float pa0 = exp2_fast(sA[2 * i] - mn), pa1 = exp2_fast(sA[2 * i + 1] - mn);
      float pb0 = exp2_fast(sB[2 * i] - mn), pb1 = exp2_fast(sB[2 * i + 1] - mn);
      s0 += pa0 + pa1;
      s1 += pb0 + pb1;
      wA[i] = cvtpk_bf16(pa0, pa1);
      wB[i] = cvtpk_bf16(pb0, pb1);
    }
    float ssum = s0 + s1;
    ssum += __shfl_xor(ssum, 32);
    lsum = lsum * corr + ssum;
    o0 *= corr;
    o1 *= corr;

    // ---- P^T B-fragments via permlane32_swap
    pswap(wA[0], wA[2]); pswap(wA[1], wA[3]);
    pswap(wA[4], wA[6]); pswap(wA[5], wA[7]);
    pswap(wB[0], wB[2]); pswap(wB[1], wB[3]);
    pswap(wB[4], wB[6]); pswap(wB[5], wB[7]);

    bf16x8 pb[4];
    pb[0] = __builtin_bit_cast(bf16x8, (u32x4){wA[0], wA[1], wA[2], wA[3]});
    pb[1] = __builtin_bit_cast(bf16x8, (u32x4){wA[4], wA[5], wA[6], wA[7]});
    pb[2] = __builtin_bit_cast(bf16x8, (u32x4){wB[0], wB[1], wB[2], wB[3]});
    pb[3] = __builtin_bit_cast(bf16x8, (u32x4){wB[4], wB[5], wB[6], wB[7]});

    // ---- PV (swapped): O^T += V^T * P^T, key-chunks of 16
#pragma unroll
    for (int c = 0; c < 4; c++) {
      bf16x8 va0 = *(const bf16x8*)(Vp + (size_t)r31 * SEQL + kv0 + c * 16 + hi * 8);
      bf16x8 va1 = *(const bf16x8*)(Vp + (size_t)(r31 + 32) * SEQL + kv0 + c * 16 + hi * 8);
      o0 = MFMA32(va0, pb[c], o0);
      o1 = MFMA32(va1, pb[c], o1);
    }
  }

  // ---- merge partials across the 4 waves ----
  Ml[w][r31] = m;
  Ll[w][r31] = lsum;
#pragma unroll
  for (int r = 0; r < 16; r++) {
    Ol[w][r][l] = o0[r];
    Ol[w][16 + r][l] = o1[r];
  }
  __syncthreads();

  if (tid < 128) {
    int w2 = tid >> 5, q = tid & 31;
    float m0 = Ml[0][q], m1 = Ml[1][q], m2 = Ml[2][q], m3 = Ml[3][q];
    float ms = fmaxf(fmaxf(m0, m1), fmaxf(m2, m3));
    float e0 = exp2_fast(m0 - ms), e1 = exp2_fast(m1 - ms);
    float e2 = exp2_fast(m2 - ms), e3 = exp2_fast(m3 - ms);
    float ls = Ll[0][q] * e0 + Ll[1][q] * e1 + Ll[2][q] * e2 + Ll[3][q] * e3;
    float ei = (w2 == 0) ? e0 : (w2 == 1) ? e1 : (w2 == 2) ? e2 : e3;
    Cl[w2][q] = ei / ls;
  }
  __syncthreads();

  {
    int q = tid >> 3, dblk = (tid & 7) * 8;
    float c0 = Cl[0][q], c1 = Cl[1][q], c2 = Cl[2][q], c3 = Cl[3][q];
    u16 ov[8];
#pragma unroll
    for (int j = 0; j < 8; j++) {
      int d = dblk + j;
      int dlocal = d & 31, dt = d >> 5;
      int h2 = (dlocal >> 2) & 1;
      int rr = (dlocal & 3) + 4 * ((dlocal >> 3) & 3) + 16 * dt;
      int ll = q + 32 * h2;
      float v = Ol[0][rr][ll] * c0 + Ol[1][rr][ll] * c1 + Ol[2][rr][ll] * c2 + Ol[3][rr][ll] * c3;
      ov[j] = f2b(v);
    }
    u16* aop = AO + ((size_t)(b * SEQL + q0 + q)) * 1024 + h * 64 + dblk;
    *(uint4*)aop = *(const uint4*)ov;
  }
}

// ---------------- launch ----------------

extern "C" void kernel_launch(void* const* d_in, const int* in_sizes, int n_in,
                              void* d_out, int out_size, void* d_ws, size_t ws_size,
                              hipStream_t stream) {
  const float* hs = (const float*)d_in[0];   // [2][2048][1024]
  const float* w1 = (const float*)d_in[1];   // [1024][3072]
  const float* b1 = (const float*)d_in[2];   // [3072]
  const float* w2 = (const float*)d_in[3];   // [1024][1024]
  const float* b2 = (const float*)d_in[4];   // [1024]
  float* out = (float*)d_out;

  char* ws = (char*)d_ws;
  const size_t MB = 1u << 20;
  u16* hsb = (u16*)(ws + 0);        // 8 MB  [4096][1024] bf16
  u16* w1t = (u16*)(ws + 8 * MB);   // 6 MB  [3072][1024] bf16
  u16* w2t = (u16*)(ws + 14 * MB);  // 2 MB  [1024][1024] bf16
  u16* Qb = (u16*)(ws + 16 * MB);   // 8 MB  [32][2048][64] bf16, pre-scaled log2e/8
  u16* Kb = (u16*)(ws + 24 * MB);   // 8 MB  [32][2048][64] bf16
  u16* Vt = (u16*)(ws + 32 * MB);   // 8 MB  [32][64][2048] bf16
  u16* AO = hsb;                    // reuse: [4096][1024] bf16

  cast_f32_bf16<<<4096, 256, 0, stream>>>(hs, hsb, 4096 * 1024 / 4);
  dim3 tb(32, 8);
  transpose_cast<<<dim3(32, 96), tb, 0, stream>>>(w1, w1t, 1024, 3072);
  transpose_cast<<<dim3(32, 32), tb, 0, stream>>>(w2, w2t, 1024, 1024);

  // qkv = hs @ w1 + b1  -> Q,K,V^T (bf16)
  gemm_bt<0><<<32 * 24, 256, 0, stream>>>(hsb, w1t, b1, Qb, Kb, Vt, nullptr,
                                          4096, 3072, 1024, 24);
  // flash attention: one q-tile per block, KV-split across 4 waves
  attn_kernel<<<2048, 256, 0, stream>>>(Qb, Kb, Vt, AO);
  // out = AO @ w2 + b2 (f32)
  gemm_bt<1><<<32 * 8, 256, 0, stream>>>(AO, w2t, b2, nullptr, nullptr, nullptr, out,
                                         4096, 1024, 1024, 8);
}

// Round 8
// 151.561 us; speedup vs baseline: 2.0734x; 1.0805x over previous
//
#include <hip/hip_runtime.h>
#include <hip/hip_bf16.h>

typedef __attribute__((ext_vector_type(8))) short bf16x8;
typedef __attribute__((ext_vector_type(4))) float f32x4;
typedef __attribute__((ext_vector_type(16))) float f32x16;
typedef __attribute__((ext_vector_type(4))) unsigned int u32x4;
typedef unsigned short u16;

#define MFMA_BF16(a, b, c) __builtin_amdgcn_mfma_f32_16x16x32_bf16(a, b, c, 0, 0, 0)
#define MFMA32(a, b, c) __builtin_amdgcn_mfma_f32_32x32x16_bf16(a, b, c, 0, 0, 0)

__device__ inline u16 f2b(float x) {
  unsigned int u = __builtin_bit_cast(unsigned int, x);
  u += 0x7fffu + ((u >> 16) & 1u);
  return (u16)(u >> 16);
}

__device__ inline float exp2_fast(float x) {
  float r;
  asm("v_exp_f32 %0, %1" : "=v"(r) : "v"(x));
  return r;
}

__device__ inline unsigned int cvtpk_bf16(float lo, float hi) {
  unsigned int r;
  asm("v_cvt_pk_bf16_f32 %0, %1, %2" : "=v"(r) : "v"(lo), "v"(hi));
  return r;
}

// v_permlane32_swap_b32 vdst, vsrc: vdst[32:63] <-> vsrc[0:31].
__device__ inline void pswap(unsigned int& dst, unsigned int& src) {
  asm("v_permlane32_swap_b32 %0, %1" : "+v"(dst), "+v"(src));
}

__device__ inline void gload16(void* lds, const void* g) {
  __builtin_amdgcn_global_load_lds((const __attribute__((address_space(1))) void*)g,
                                   (__attribute__((address_space(3))) void*)lds,
                                   16, 0, 0);
}

// ---------------- prep kernels ----------------

__global__ __launch_bounds__(256) void cast_f32_bf16(const float* __restrict__ src,
                                                     u16* __restrict__ dst, int n4) {
  int i = blockIdx.x * blockDim.x + threadIdx.x;
  if (i < n4) {
    float4 v = ((const float4*)src)[i];
    ushort4 o;
    o.x = f2b(v.x); o.y = f2b(v.y); o.z = f2b(v.z); o.w = f2b(v.w);
    ((ushort4*)dst)[i] = o;
  }
}

// dst[n][k] = bf16(src[k][n]); src is [K][N] f32 row-major.
__global__ __launch_bounds__(256) void transpose_cast(const float* __restrict__ src,
                                                      u16* __restrict__ dst, int K, int N) {
  __shared__ float t[32][33];
  int k0 = blockIdx.x * 32, n0 = blockIdx.y * 32;
  int tx = threadIdx.x, ty = threadIdx.y;  // 32 x 8
#pragma unroll
  for (int i = 0; i < 4; i++) t[ty + i * 8][tx] = src[(size_t)(k0 + ty + i * 8) * N + n0 + tx];
  __syncthreads();
#pragma unroll
  for (int i = 0; i < 4; i++)
    dst[(size_t)(n0 + ty + i * 8) * K + k0 + tx] = f2b(t[tx][ty + i * 8]);
}

// ---------------- GEMM (m97-style 128x128 tile, BK=32) ----------------
// Q is pre-scaled by log2(e)/8 so attention works in exp2 domain.
// K/V are written in MFMA-fragment-ready layouts:
//  Kf[bh][tile=s>>6][j][lane][e]: element K[s][d] at j=(key>=32)*4+(d>>4),
//      lane=((d>>3)&1)<<5 | (key&31), e=d&7   (key=s&63)
//  Vf[bh][tile][j][lane][e]:      element V[s][d] at j=(d>=32)*4+(key>>4),
//      lane=((key>>3)&1)<<5 | (d&31), e=key&7
#define QSCALE 0.1803368801f

template <int EPI>
__global__ __launch_bounds__(256) void gemm_bt(
    const u16* __restrict__ A, const u16* __restrict__ BT, const float* __restrict__ bias,
    u16* __restrict__ oQ, u16* __restrict__ oK, u16* __restrict__ oVf,
    float* __restrict__ oF, int M, int N, int K, int nbx) {
  __shared__ __align__(16) u16 As[128 * 32];
  __shared__ __align__(16) u16 Bs[128 * 32];
  int tid = threadIdx.x;
  int wv = tid >> 6, lane = tid & 63, lr = lane & 15, lg = lane >> 4;
  int bx = blockIdx.x % nbx, by = blockIdx.x / nbx;
  int m0 = by * 128, n0 = bx * 128;
  int wr = (wv >> 1) * 64, wc = (wv & 1) * 64;

  f32x4 acc[4][4] = {};

  for (int k0 = 0; k0 < K; k0 += 32) {
#pragma unroll
    for (int j = 0; j < 2; j++) {
      int li = (wv * 2 + j) * 64 + lane;   // 0..511
      int row = li >> 2, kc = (li & 3) * 8;
      gload16(As + (wv * 2 + j) * 512, A + (size_t)(m0 + row) * K + k0 + kc);
      gload16(Bs + (wv * 2 + j) * 512, BT + (size_t)(n0 + row) * K + k0 + kc);
    }
    __syncthreads();
    bf16x8 a[4], b[4];
#pragma unroll
    for (int i = 0; i < 4; i++) a[i] = *(const bf16x8*)&As[(wr + i * 16 + lr) * 32 + lg * 8];
#pragma unroll
    for (int j = 0; j < 4; j++) b[j] = *(const bf16x8*)&Bs[(wc + j * 16 + lr) * 32 + lg * 8];
#pragma unroll
    for (int i = 0; i < 4; i++)
#pragma unroll
      for (int j = 0; j < 4; j++) acc[i][j] = MFMA_BF16(a[i], b[j], acc[i][j]);
    __syncthreads();
  }

#pragma unroll
  for (int i = 0; i < 4; i++) {
#pragma unroll
    for (int j = 0; j < 4; j++) {
#pragma unroll
      for (int jj = 0; jj < 4; jj++) {
        int row = m0 + wr + i * 16 + lg * 4 + jj;  // m index
        int col = n0 + wc + j * 16 + lr;           // n index
        float v = acc[i][j][jj] + bias[col];
        if (EPI == 0) {
          int bb = row >> 11, s = row & 2047;
          int tile = s >> 6, key = s & 63;
          if (col < 1024) {
            oQ[((size_t)((bb * 16 + (col >> 6)) * 2048 + s)) * 64 + (col & 63)] = f2b(v * QSCALE);
          } else if (col < 2048) {
            int c = col - 1024;
            int hh = c >> 6, d = c & 63;
            int jf = ((key >> 5) << 2) + (d >> 4);
            int ln = (((d >> 3) & 1) << 5) | (key & 31);
            oK[(size_t)(bb * 16 + hh) * 131072 + tile * 4096 + jf * 512 + ln * 8 + (d & 7)] =
                f2b(v);
          } else {
            int c = col - 2048;
            int hh = c >> 6, d = c & 63;
            int jf = ((d >> 5) << 2) + (key >> 4);
            int ln = (((key >> 3) & 1) << 5) | (d & 31);
            oVf[(size_t)(bb * 16 + hh) * 131072 + tile * 4096 + jf * 512 + ln * 8 + (key & 7)] =
                f2b(v);
          }
        } else {
          oF[(size_t)row * N + col] = v;
        }
      }
    }
  }
}

// ---------------- flash attention (swapped 32x32, KV-split, fragment-layout KV) ----------------
// Q: [bh][S][64] bf16 pre-scaled by log2e/8. Kf/Vf: fragment-ready (see above).
// One 32-row q-tile per BLOCK; 4 waves split causal KV range by stride-4 step
// interleave; partials merged through LDS in two d-half passes (18KB LDS).
#define SEQL 2048
#define FIRST_END 682
#define SECOND_END 1365
#define LOG2F16 0.6780719051f

__global__ __launch_bounds__(256) void attn_kernel(const u16* __restrict__ Qb,
                                                   const u16* __restrict__ Kf,
                                                   const u16* __restrict__ Vf,
                                                   u16* __restrict__ AO) {
  __shared__ float Ol[4][16][66];   // [wave][reg r][lane], padded
  __shared__ float Ml[4][32], Ll[4][32], Cl[4][32];

  int tid = threadIdx.x;
  int w = tid >> 6, l = tid & 63;
  int r31 = l & 31, hi = l >> 5;

  // 2048 blocks: XCD gets 4 bh x 64 tiles; big tiles (qt=63) launch first.
  int xcd = blockIdx.x & 7, slot = blockIdx.x >> 3;   // slot 0..255
  int bh = xcd * 4 + (slot >> 6);
  int qt = 63 - (slot & 63);
  int q0 = qt * 32;
  int h = bh & 15, b = bh >> 4;

  // Q fragments (B-operand of swapped QK): lane holds Q[q=r31][kb*16+hi*8 .. +7]
  const u16* Qp = Qb + ((size_t)bh * SEQL + q0 + r31) * 64 + hi * 8;
  bf16x8 qa[4];
#pragma unroll
  for (int kb = 0; kb < 4; kb++) qa[kb] = *(const bf16x8*)(Qp + kb * 16);

  const u16* Kfp = Kf + (size_t)bh * 131072;
  const u16* Vfp = Vf + (size_t)bh * 131072;

  f32x16 o0 = {}, o1 = {};   // O^T tiles: d = dt*32 + (reg&3)+8*(reg>>2)+4*hi, q = r31
  float m = -1e30f, lsum = 0.f;

  const int N = (q0 + 95) >> 6;   // total 64-key steps for this q-tile
  const bool hasb = (h < 3);

  for (int t = w; t < N; t += 4) {
    const int kv0 = t << 6;
    const bool last = (t == N - 1);
    const u16* kt = Kfp + (size_t)t * 4096;
    const u16* vt = Vfp + (size_t)t * 4096;

    // ---- QK^T (swapped): sA/sB[reg] = S^T[key][q=r31]; coalesced 1KB loads
    bf16x8 ka[4], kb2[4];
#pragma unroll
    for (int kb = 0; kb < 4; kb++) {
      ka[kb]  = *(const bf16x8*)(kt + kb * 512 + l * 8);
      kb2[kb] = *(const bf16x8*)(kt + (4 + kb) * 512 + l * 8);
    }
    f32x16 sA = {}, sB = {};
#pragma unroll
    for (int kb = 0; kb < 4; kb++) sA = MFMA32(ka[kb], qa[kb], sA);
#pragma unroll
    for (int kb = 0; kb < 4; kb++) sB = MFMA32(kb2[kb], qa[kb], sB);

    if (hasb) {
#pragma unroll
      for (int r = 0; r < 16; r++) {
        int kA = kv0 + ((r & 3) + 8 * (r >> 2) + 4 * hi);
        int kB = kA + 32;
        int rA = (kA < FIRST_END) ? 0 : (kA < SECOND_END) ? 1 : 2;
        int rB = (kB < FIRST_END) ? 0 : (kB < SECOND_END) ? 1 : 2;
        if (rA == h) sA[r] += LOG2F16;
        if (rB == h) sB[r] += LOG2F16;
      }
    }
    if (last) {
      int q = q0 + r31;
#pragma unroll
      for (int r = 0; r < 16; r++) {
        int kA = kv0 + ((r & 3) + 8 * (r >> 2) + 4 * hi);
        if (kA > q) sA[r] = -1e30f;
        if (kA + 32 > q) sB[r] = -1e30f;
      }
    }

    // ---- online softmax (lane-local row, one cross-lane exchange)
#define MAX4(v, i) fmaxf(fmaxf(v[i], v[i + 1]), fmaxf(v[i + 2], v[i + 3]))
    float mA = fmaxf(fmaxf(MAX4(sA, 0), MAX4(sA, 4)), fmaxf(MAX4(sA, 8), MAX4(sA, 12)));
    float mB = fmaxf(fmaxf(MAX4(sB, 0), MAX4(sB, 4)), fmaxf(MAX4(sB, 8), MAX4(sB, 12)));
    float mx = fmaxf(mA, mB);
    mx = fmaxf(mx, __shfl_xor(mx, 32));
    float mn = fmaxf(m, mx);
    float corr = exp2_fast(m - mn);
    m = mn;

    unsigned int wA[8], wB[8];
    float s0 = 0.f, s1 = 0.f;
#pragma unroll
    for (int i = 0; i < 8; i++) {
      float pa0 = exp2_fast(sA[2 * i] - mn), pa1 = exp2_fast(sA[2 * i + 1] - mn);
      float pb0 = exp2_fast(sB[2 * i] - mn), pb1 = exp2_fast(sB[2 * i + 1] - mn);
      s0 += pa0 + pa1;
      s1 += pb0 + pb1;
      wA[i] = cvtpk_bf16(pa0, pa1);
      wB[i] = cvtpk_bf16(pb0, pb1);
    }
    float ssum = s0 + s1;
    ssum += __shfl_xor(ssum, 32);
    lsum = lsum * corr + ssum;
    o0 *= corr;
    o1 *= corr;

    // ---- P^T B-fragments via permlane32_swap
    pswap(wA[0], wA[2]); pswap(wA[1], wA[3]);
    pswap(wA[4], wA[6]); pswap(wA[5], wA[7]);
    pswap(wB[0], wB[2]); pswap(wB[1], wB[3]);
    pswap(wB[4], wB[6]); pswap(wB[5], wB[7]);

    bf16x8 pb[4];
    pb[0] = __builtin_bit_cast(bf16x8, (u32x4){wA[0], wA[1], wA[2], wA[3]});
    pb[1] = __builtin_bit_cast(bf16x8, (u32x4){wA[4], wA[5], wA[6], wA[7]});
    pb[2] = __builtin_bit_cast(bf16x8, (u32x4){wB[0], wB[1], wB[2], wB[3]});
    pb[3] = __builtin_bit_cast(bf16x8, (u32x4){wB[4], wB[5], wB[6], wB[7]});

    // ---- PV (swapped): O^T += V^T * P^T; coalesced 1KB loads
#pragma unroll
    for (int c = 0; c < 4; c++) {
      bf16x8 va0 = *(const bf16x8*)(vt + c * 512 + l * 8);
      bf16x8 va1 = *(const bf16x8*)(vt + (4 + c) * 512 + l * 8);
      o0 = MFMA32(va0, pb[c], o0);
      o1 = MFMA32(va1, pb[c], o1);
    }
  }

  // ---- merge partials across the 4 waves (2 passes over d-halves) ----
  Ml[w][r31] = m;
  Ll[w][r31] = lsum;
#pragma unroll
  for (int r = 0; r < 16; r++) Ol[w][r][l] = o0[r];
  __syncthreads();

  if (tid < 128) {
    int w2 = tid >> 5, q = tid & 31;
    float m0 = Ml[0][q], m1 = Ml[1][q], m2 = Ml[2][q], m3 = Ml[3][q];
    float ms = fmaxf(fmaxf(m0, m1), fmaxf(m2, m3));
    float e0 = exp2_fast(m0 - ms), e1 = exp2_fast(m1 - ms);
    float e2 = exp2_fast(m2 - ms), e3 = exp2_fast(m3 - ms);
    float ls = Ll[0][q] * e0 + Ll[1][q] * e1 + Ll[2][q] * e2 + Ll[3][q] * e3;
    float ei = (w2 == 0) ? e0 : (w2 == 1) ? e1 : (w2 == 2) ? e2 : e3;
    Cl[w2][q] = ei / ls;
  }
  __syncthreads();

  int mq = tid >> 3, md = (tid & 7) * 4;
  float c0 = Cl[0][mq], c1 = Cl[1][mq], c2 = Cl[2][mq], c3 = Cl[3][mq];
  u16* aop = AO + ((size_t)(b * SEQL + q0 + mq)) * 1024 + h * 64;

  {
    u16 ov[4];
#pragma unroll
    for (int j = 0; j < 4; j++) {
      int d = md + j;
      int h2 = (d >> 2) & 1, rr = (d & 3) + 4 * (d >> 3);
      int ll2 = mq + 32 * h2;
      ov[j] = f2b(Ol[0][rr][ll2] * c0 + Ol[1][rr][ll2] * c1 +
                  Ol[2][rr][ll2] * c2 + Ol[3][rr][ll2] * c3);
    }
    *(uint2*)(aop + md) = *(const uint2*)ov;
  }
  __syncthreads();
#pragma unroll
  for (int r = 0; r < 16; r++) Ol[w][r][l] = o1[r];
  __syncthreads();
  {
    u16 ov[4];
#pragma unroll
    for (int j = 0; j < 4; j++) {
      int d = md + j;
      int h2 = (d >> 2) & 1, rr = (d & 3) + 4 * (d >> 3);
      int ll2 = mq + 32 * h2;
      ov[j] = f2b(Ol[0][rr][ll2] * c0 + Ol[1][rr][ll2] * c1 +
                  Ol[2][rr][ll2] * c2 + Ol[3][rr][ll2] * c3);
    }
    *(uint2*)(aop + 32 + md) = *(const uint2*)ov;
  }
}

// ---------------- launch ----------------

extern "C" void kernel_launch(void* const* d_in, const int* in_sizes, int n_in,
                              void* d_out, int out_size, void* d_ws, size_t ws_size,
                              hipStream_t stream) {
  const float* hs = (const float*)d_in[0];   // [2][2048][1024]
  const float* w1 = (const float*)d_in[1];   // [1024][3072]
  const float* b1 = (const float*)d_in[2];   // [3072]
  const float* w2 = (const float*)d_in[3];   // [1024][1024]
  const float* b2 = (const float*)d_in[4];   // [1024]
  float* out = (float*)d_out;

  char* ws = (char*)d_ws;
  const size_t MB = 1u << 20;
  u16* hsb = (u16*)(ws + 0);        // 8 MB  [4096][1024] bf16
  u16* w1t = (u16*)(ws + 8 * MB);   // 6 MB  [3072][1024] bf16
  u16* w2t = (u16*)(ws + 14 * MB);  // 2 MB  [1024][1024] bf16
  u16* Qb = (u16*)(ws + 16 * MB);   // 8 MB  [32][2048][64] bf16, pre-scaled log2e/8
  u16* Kf = (u16*)(ws + 24 * MB);   // 8 MB  fragment-ready K
  u16* Vf = (u16*)(ws + 32 * MB);   // 8 MB  fragment-ready V^T
  u16* AO = hsb;                    // reuse: [4096][1024] bf16

  cast_f32_bf16<<<4096, 256, 0, stream>>>(hs, hsb, 4096 * 1024 / 4);
  dim3 tb(32, 8);
  transpose_cast<<<dim3(32, 96), tb, 0, stream>>>(w1, w1t, 1024, 3072);
  transpose_cast<<<dim3(32, 32), tb, 0, stream>>>(w2, w2t, 1024, 1024);

  // qkv = hs @ w1 + b1  -> Q, Kf, Vf (bf16)
  gemm_bt<0><<<32 * 24, 256, 0, stream>>>(hsb, w1t, b1, Qb, Kf, Vf, nullptr,
                                          4096, 3072, 1024, 24);
  // flash attention: one q-tile per block, KV-split across 4 waves
  attn_kernel<<<2048, 256, 0, stream>>>(Qb, Kf, Vf, AO);
  // out = AO @ w2 + b2 (f32)
  gemm_bt<1><<<32 * 8, 256, 0, stream>>>(AO, w2t, b2, nullptr, nullptr, nullptr, out,
                                         4096, 1024, 1024, 8);
}

// Round 9
// 137.670 us; speedup vs baseline: 2.2826x; 1.1009x over previous
//
#include <hip/hip_runtime.h>
#include <hip/hip_bf16.h>

typedef __attribute__((ext_vector_type(8))) short bf16x8;
typedef __attribute__((ext_vector_type(4))) float f32x4;
typedef __attribute__((ext_vector_type(16))) float f32x16;
typedef __attribute__((ext_vector_type(4))) unsigned int u32x4;
typedef unsigned short u16;

#define MFMA_BF16(a, b, c) __builtin_amdgcn_mfma_f32_16x16x32_bf16(a, b, c, 0, 0, 0)
#define MFMA32(a, b, c) __builtin_amdgcn_mfma_f32_32x32x16_bf16(a, b, c, 0, 0, 0)

__device__ inline u16 f2b(float x) {
  unsigned int u = __builtin_bit_cast(unsigned int, x);
  u += 0x7fffu + ((u >> 16) & 1u);
  return (u16)(u >> 16);
}

__device__ inline float exp2_fast(float x) {
  float r;
  asm("v_exp_f32 %0, %1" : "=v"(r) : "v"(x));
  return r;
}

__device__ inline unsigned int cvtpk_bf16(float lo, float hi) {
  unsigned int r;
  asm("v_cvt_pk_bf16_f32 %0, %1, %2" : "=v"(r) : "v"(lo), "v"(hi));
  return r;
}

// v_permlane32_swap_b32 vdst, vsrc: vdst[32:63] <-> vsrc[0:31].
__device__ inline void pswap(unsigned int& dst, unsigned int& src) {
  asm("v_permlane32_swap_b32 %0, %1" : "+v"(dst), "+v"(src));
}

__device__ inline void gload16(void* lds, const void* g) {
  __builtin_amdgcn_global_load_lds((const __attribute__((address_space(1))) void*)g,
                                   (__attribute__((address_space(3))) void*)lds,
                                   16, 0, 0);
}

// ---------------- prep kernels ----------------

__global__ __launch_bounds__(256) void cast_f32_bf16(const float* __restrict__ src,
                                                     u16* __restrict__ dst, int n4) {
  int i = blockIdx.x * blockDim.x + threadIdx.x;
  if (i < n4) {
    float4 v = ((const float4*)src)[i];
    ushort4 o;
    o.x = f2b(v.x); o.y = f2b(v.y); o.z = f2b(v.z); o.w = f2b(v.w);
    ((ushort4*)dst)[i] = o;
  }
}

// dst[n][k] = bf16(src[k][n]); src is [K][N] f32 row-major.
__global__ __launch_bounds__(256) void transpose_cast(const float* __restrict__ src,
                                                      u16* __restrict__ dst, int K, int N) {
  __shared__ float t[32][33];
  int k0 = blockIdx.x * 32, n0 = blockIdx.y * 32;
  int tx = threadIdx.x, ty = threadIdx.y;  // 32 x 8
#pragma unroll
  for (int i = 0; i < 4; i++) t[ty + i * 8][tx] = src[(size_t)(k0 + ty + i * 8) * N + n0 + tx];
  __syncthreads();
#pragma unroll
  for (int i = 0; i < 4; i++)
    dst[(size_t)(n0 + ty + i * 8) * K + k0 + tx] = f2b(t[tx][ty + i * 8]);
}

// ---------------- GEMM (128x128 tile, BK=64, T2 XOR-swizzled LDS) ----------------
// LDS layout [128][64] bf16 (128B rows). Both-sides swizzle (rule #21):
// linear global_load_lds dest + inverse-swizzled global SOURCE + swizzled
// ds_read: byte ^= ((row&7)<<4). 16-way bank conflict -> ~2-way (free).
// Q is pre-scaled by log2(e)/8 so attention works in exp2 domain.
// K/V are written in MFMA-fragment-ready layouts (see round-7 comment).
#define QSCALE 0.1803368801f

template <int EPI>
__global__ __launch_bounds__(256) void gemm_bt(
    const u16* __restrict__ A, const u16* __restrict__ BT, const float* __restrict__ bias,
    u16* __restrict__ oQ, u16* __restrict__ oK, u16* __restrict__ oVf,
    float* __restrict__ oF, int M, int N, int K, int nbx) {
  __shared__ __align__(16) u16 As[128 * 64];
  __shared__ __align__(16) u16 Bs[128 * 64];
  int tid = threadIdx.x;
  int wv = tid >> 6, lane = tid & 63, lr = lane & 15, lg = lane >> 4;
  int bx = blockIdx.x % nbx, by = blockIdx.x / nbx;
  int m0 = by * 128, n0 = bx * 128;
  int wr = (wv >> 1) * 64, wc = (wv & 1) * 64;

  f32x4 acc[4][4] = {};

  for (int k0 = 0; k0 < K; k0 += 64) {
    // stage A,B tiles: 1024 16B-chunks each; thread's chunk li = j*256+tid.
    // dest linear (wave-uniform base + lane*16); source column pre-swizzled.
#pragma unroll
    for (int j = 0; j < 4; j++) {
      int li = j * 256 + tid;
      int row = li >> 3;
      int cb = ((li & 7) * 16) ^ ((row & 7) << 4);
      gload16((char*)As + j * 4096 + wv * 1024,
              (const char*)(A + (size_t)(m0 + row) * K + k0) + cb);
      gload16((char*)Bs + j * 4096 + wv * 1024,
              (const char*)(BT + (size_t)(n0 + row) * K + k0) + cb);
    }
    __syncthreads();
#pragma unroll
    for (int kk = 0; kk < 2; kk++) {
      bf16x8 a[4], b[4];
#pragma unroll
      for (int i = 0; i < 4; i++) {
        int row = wr + i * 16 + lr;
        a[i] = *(const bf16x8*)((const char*)As + row * 128 +
                                ((kk * 64 + lg * 16) ^ ((row & 7) << 4)));
      }
#pragma unroll
      for (int j = 0; j < 4; j++) {
        int row = wc + j * 16 + lr;
        b[j] = *(const bf16x8*)((const char*)Bs + row * 128 +
                                ((kk * 64 + lg * 16) ^ ((row & 7) << 4)));
      }
#pragma unroll
      for (int i = 0; i < 4; i++)
#pragma unroll
        for (int j = 0; j < 4; j++) acc[i][j] = MFMA_BF16(a[i], b[j], acc[i][j]);
    }
    __syncthreads();
  }

#pragma unroll
  for (int i = 0; i < 4; i++) {
#pragma unroll
    for (int j = 0; j < 4; j++) {
#pragma unroll
      for (int jj = 0; jj < 4; jj++) {
        int row = m0 + wr + i * 16 + lg * 4 + jj;  // m index
        int col = n0 + wc + j * 16 + lr;           // n index
        float v = acc[i][j][jj] + bias[col];
        if (EPI == 0) {
          int bb = row >> 11, s = row & 2047;
          int tile = s >> 6, key = s & 63;
          if (col < 1024) {
            oQ[((size_t)((bb * 16 + (col >> 6)) * 2048 + s)) * 64 + (col & 63)] = f2b(v * QSCALE);
          } else if (col < 2048) {
            int c = col - 1024;
            int hh = c >> 6, d = c & 63;
            int jf = ((key >> 5) << 2) + (d >> 4);
            int ln = (((d >> 3) & 1) << 5) | (key & 31);
            oK[(size_t)(bb * 16 + hh) * 131072 + tile * 4096 + jf * 512 + ln * 8 + (d & 7)] =
                f2b(v);
          } else {
            int c = col - 2048;
            int hh = c >> 6, d = c & 63;
            int jf = ((d >> 5) << 2) + (key >> 4);
            int ln = (((key >> 3) & 1) << 5) | (d & 31);
            oVf[(size_t)(bb * 16 + hh) * 131072 + tile * 4096 + jf * 512 + ln * 8 + (key & 7)] =
                f2b(v);
          }
        } else {
          oF[(size_t)row * N + col] = v;
        }
      }
    }
  }
}

// ---------------- flash attention (swapped 32x32, KV-split, fragment-layout KV) ----------------
// Q: [bh][S][64] bf16 pre-scaled by log2e/8. Kf/Vf: fragment-ready.
// One 32-row q-tile per BLOCK; 4 waves split causal KV range by stride-4 step
// interleave; partials merged through LDS in two d-half passes (18KB LDS).
#define SEQL 2048
#define FIRST_END 682
#define SECOND_END 1365
#define LOG2F16 0.6780719051f

__global__ __launch_bounds__(256) void attn_kernel(const u16* __restrict__ Qb,
                                                   const u16* __restrict__ Kf,
                                                   const u16* __restrict__ Vf,
                                                   u16* __restrict__ AO) {
  __shared__ float Ol[4][16][66];   // [wave][reg r][lane], padded
  __shared__ float Ml[4][32], Ll[4][32], Cl[4][32];

  int tid = threadIdx.x;
  int w = tid >> 6, l = tid & 63;
  int r31 = l & 31, hi = l >> 5;

  // 2048 blocks: XCD gets 4 bh x 64 tiles; big tiles (qt=63) launch first.
  int xcd = blockIdx.x & 7, slot = blockIdx.x >> 3;   // slot 0..255
  int bh = xcd * 4 + (slot >> 6);
  int qt = 63 - (slot & 63);
  int q0 = qt * 32;
  int h = bh & 15, b = bh >> 4;

  // Q fragments (B-operand of swapped QK): lane holds Q[q=r31][kb*16+hi*8 .. +7]
  const u16* Qp = Qb + ((size_t)bh * SEQL + q0 + r31) * 64 + hi * 8;
  bf16x8 qa[4];
#pragma unroll
  for (int kb = 0; kb < 4; kb++) qa[kb] = *(const bf16x8*)(Qp + kb * 16);

  const u16* Kfp = Kf + (size_t)bh * 131072;
  const u16* Vfp = Vf + (size_t)bh * 131072;

  f32x16 o0 = {}, o1 = {};   // O^T tiles: d = dt*32 + (reg&3)+8*(reg>>2)+4*hi, q = r31
  float m = -1e30f, lsum = 0.f;

  const int N = (q0 + 95) >> 6;   // total 64-key steps for this q-tile
  const bool hasb = (h < 3);

  for (int t = w; t < N; t += 4) {
    const int kv0 = t << 6;
    const bool last = (t == N - 1);
    const u16* kt = Kfp + (size_t)t * 4096;
    const u16* vt = Vfp + (size_t)t * 4096;

    // ---- QK^T (swapped): sA/sB[reg] = S^T[key][q=r31]; coalesced 1KB loads
    bf16x8 ka[4], kb2[4];
#pragma unroll
    for (int kb = 0; kb < 4; kb++) {
      ka[kb]  = *(const bf16x8*)(kt + kb * 512 + l * 8);
      kb2[kb] = *(const bf16x8*)(kt + (4 + kb) * 512 + l * 8);
    }
    f32x16 sA = {}, sB = {};
#pragma unroll
    for (int kb = 0; kb < 4; kb++) sA = MFMA32(ka[kb], qa[kb], sA);
#pragma unroll
    for (int kb = 0; kb < 4; kb++) sB = MFMA32(kb2[kb], qa[kb], sB);

    if (hasb) {
#pragma unroll
      for (int r = 0; r < 16; r++) {
        int kA = kv0 + ((r & 3) + 8 * (r >> 2) + 4 * hi);
        int kB = kA + 32;
        int rA = (kA < FIRST_END) ? 0 : (kA < SECOND_END) ? 1 : 2;
        int rB = (kB < FIRST_END) ? 0 : (kB < SECOND_END) ? 1 : 2;
        if (rA == h) sA[r] += LOG2F16;
        if (rB == h) sB[r] += LOG2F16;
      }
    }
    if (last) {
      int q = q0 + r31;
#pragma unroll
      for (int r = 0; r < 16; r++) {
        int kA = kv0 + ((r & 3) + 8 * (r >> 2) + 4 * hi);
        if (kA > q) sA[r] = -1e30f;
        if (kA + 32 > q) sB[r] = -1e30f;
      }
    }

    // ---- online softmax (lane-local row, one cross-lane exchange)
#define MAX4(v, i) fmaxf(fmaxf(v[i], v[i + 1]), fmaxf(v[i + 2], v[i + 3]))
    float mA = fmaxf(fmaxf(MAX4(sA, 0), MAX4(sA, 4)), fmaxf(MAX4(sA, 8), MAX4(sA, 12)));
    float mB = fmaxf(fmaxf(MAX4(sB, 0), MAX4(sB, 4)), fmaxf(MAX4(sB, 8), MAX4(sB, 12)));
    float mx = fmaxf(mA, mB);
    mx = fmaxf(mx, __shfl_xor(mx, 32));
    float mn = fmaxf(m, mx);
    float corr = exp2_fast(m - mn);
    m = mn;

    unsigned int wA[8], wB[8];
    float s0 = 0.f, s1 = 0.f;
#pragma unroll
    for (int i = 0; i < 8; i++) {
      float pa0 = exp2_fast(sA[2 * i] - mn), pa1 = exp2_fast(sA[2 * i + 1] - mn);
      float pb0 = exp2_fast(sB[2 * i] - mn), pb1 = exp2_fast(sB[2 * i + 1] - mn);
      s0 += pa0 + pa1;
      s1 += pb0 + pb1;
      wA[i] = cvtpk_bf16(pa0, pa1);
      wB[i] = cvtpk_bf16(pb0, pb1);
    }
    float ssum = s0 + s1;
    ssum += __shfl_xor(ssum, 32);
    lsum = lsum * corr + ssum;
    o0 *= corr;
    o1 *= corr;

    // ---- P^T B-fragments via permlane32_swap
    pswap(wA[0], wA[2]); pswap(wA[1], wA[3]);
    pswap(wA[4], wA[6]); pswap(wA[5], wA[7]);
    pswap(wB[0], wB[2]); pswap(wB[1], wB[3]);
    pswap(wB[4], wB[6]); pswap(wB[5], wB[7]);

    bf16x8 pb[4];
    pb[0] = __builtin_bit_cast(bf16x8, (u32x4){wA[0], wA[1], wA[2], wA[3]});
    pb[1] = __builtin_bit_cast(bf16x8, (u32x4){wA[4], wA[5], wA[6], wA[7]});
    pb[2] = __builtin_bit_cast(bf16x8, (u32x4){wB[0], wB[1], wB[2], wB[3]});
    pb[3] = __builtin_bit_cast(bf16x8, (u32x4){wB[4], wB[5], wB[6], wB[7]});

    // ---- PV (swapped): O^T += V^T * P^T; coalesced 1KB loads
#pragma unroll
    for (int c = 0; c < 4; c++) {
      bf16x8 va0 = *(const bf16x8*)(vt + c * 512 + l * 8);
      bf16x8 va1 = *(const bf16x8*)(vt + (4 + c) * 512 + l * 8);
      o0 = MFMA32(va0, pb[c], o0);
      o1 = MFMA32(va1, pb[c], o1);
    }
  }

  // ---- merge partials across the 4 waves (2 passes over d-halves) ----
  Ml[w][r31] = m;
  Ll[w][r31] = lsum;
#pragma unroll
  for (int r = 0; r < 16; r++) Ol[w][r][l] = o0[r];
  __syncthreads();

  if (tid < 128) {
    int w2 = tid >> 5, q = tid & 31;
    float m0 = Ml[0][q], m1 = Ml[1][q], m2 = Ml[2][q], m3 = Ml[3][q];
    float ms = fmaxf(fmaxf(m0, m1), fmaxf(m2, m3));
    float e0 = exp2_fast(m0 - ms), e1 = exp2_fast(m1 - ms);
    float e2 = exp2_fast(m2 - ms), e3 = exp2_fast(m3 - ms);
    float ls = Ll[0][q] * e0 + Ll[1][q] * e1 + Ll[2][q] * e2 + Ll[3][q] * e3;
    float ei = (w2 == 0) ? e0 : (w2 == 1) ? e1 : (w2 == 2) ? e2 : e3;
    Cl[w2][q] = ei / ls;
  }
  __syncthreads();

  int mq = tid >> 3, md = (tid & 7) * 4;
  float c0 = Cl[0][mq], c1 = Cl[1][mq], c2 = Cl[2][mq], c3 = Cl[3][mq];
  u16* aop = AO + ((size_t)(b * SEQL + q0 + mq)) * 1024 + h * 64;

  {
    u16 ov[4];
#pragma unroll
    for (int j = 0; j < 4; j++) {
      int d = md + j;
      int h2 = (d >> 2) & 1, rr = (d & 3) + 4 * (d >> 3);
      int ll2 = mq + 32 * h2;
      ov[j] = f2b(Ol[0][rr][ll2] * c0 + Ol[1][rr][ll2] * c1 +
                  Ol[2][rr][ll2] * c2 + Ol[3][rr][ll2] * c3);
    }
    *(uint2*)(aop + md) = *(const uint2*)ov;
  }
  __syncthreads();
#pragma unroll
  for (int r = 0; r < 16; r++) Ol[w][r][l] = o1[r];
  __syncthreads();
  {
    u16 ov[4];
#pragma unroll
    for (int j = 0; j < 4; j++) {
      int d = md + j;
      int h2 = (d >> 2) & 1, rr = (d & 3) + 4 * (d >> 3);
      int ll2 = mq + 32 * h2;
      ov[j] = f2b(Ol[0][rr][ll2] * c0 + Ol[1][rr][ll2] * c1 +
                  Ol[2][rr][ll2] * c2 + Ol[3][rr][ll2] * c3);
    }
    *(uint2*)(aop + 32 + md) = *(const uint2*)ov;
  }
}

// ---------------- launch ----------------

extern "C" void kernel_launch(void* const* d_in, const int* in_sizes, int n_in,
                              void* d_out, int out_size, void* d_ws, size_t ws_size,
                              hipStream_t stream) {
  const float* hs = (const float*)d_in[0];   // [2][2048][1024]
  const float* w1 = (const float*)d_in[1];   // [1024][3072]
  const float* b1 = (const float*)d_in[2];   // [3072]
  const float* w2 = (const float*)d_in[3];   // [1024][1024]
  const float* b2 = (const float*)d_in[4];   // [1024]
  float* out = (float*)d_out;

  char* ws = (char*)d_ws;
  const size_t MB = 1u << 20;
  u16* hsb = (u16*)(ws + 0);        // 8 MB  [4096][1024] bf16
  u16* w1t = (u16*)(ws + 8 * MB);   // 6 MB  [3072][1024] bf16
  u16* w2t = (u16*)(ws + 14 * MB);  // 2 MB  [1024][1024] bf16
  u16* Qb = (u16*)(ws + 16 * MB);   // 8 MB  [32][2048][64] bf16, pre-scaled log2e/8
  u16* Kf = (u16*)(ws + 24 * MB);   // 8 MB  fragment-ready K
  u16* Vf = (u16*)(ws + 32 * MB);   // 8 MB  fragment-ready V^T
  u16* AO = hsb;                    // reuse: [4096][1024] bf16

  cast_f32_bf16<<<4096, 256, 0, stream>>>(hs, hsb, 4096 * 1024 / 4);
  dim3 tb(32, 8);
  transpose_cast<<<dim3(32, 96), tb, 0, stream>>>(w1, w1t, 1024, 3072);
  transpose_cast<<<dim3(32, 32), tb, 0, stream>>>(w2, w2t, 1024, 1024);

  // qkv = hs @ w1 + b1  -> Q, Kf, Vf (bf16)
  gemm_bt<0><<<32 * 24, 256, 0, stream>>>(hsb, w1t, b1, Qb, Kf, Vf, nullptr,
                                          4096, 3072, 1024, 24);
  // flash attention: one q-tile per block, KV-split across 4 waves
  attn_kernel<<<2048, 256, 0, stream>>>(Qb, Kf, Vf, AO);
  // out = AO @ w2 + b2 (f32)
  gemm_bt<1><<<32 * 8, 256, 0, stream>>>(AO, w2t, b2, nullptr, nullptr, nullptr, out,
                                         4096, 1024, 1024, 8);
}

// Round 10
// 130.597 us; speedup vs baseline: 2.4063x; 1.0542x over previous
//
#include <hip/hip_runtime.h>
#include <hip/hip_bf16.h>

typedef __attribute__((ext_vector_type(8))) short bf16x8;
typedef __attribute__((ext_vector_type(4))) float f32x4;
typedef __attribute__((ext_vector_type(16))) float f32x16;
typedef __attribute__((ext_vector_type(4))) unsigned int u32x4;
typedef unsigned short u16;

#define MFMA_BF16(a, b, c) __builtin_amdgcn_mfma_f32_16x16x32_bf16(a, b, c, 0, 0, 0)
#define MFMA32(a, b, c) __builtin_amdgcn_mfma_f32_32x32x16_bf16(a, b, c, 0, 0, 0)

__device__ inline u16 f2b(float x) {
  unsigned int u = __builtin_bit_cast(unsigned int, x);
  u += 0x7fffu + ((u >> 16) & 1u);
  return (u16)(u >> 16);
}

__device__ inline float exp2_fast(float x) {
  float r;
  asm("v_exp_f32 %0, %1" : "=v"(r) : "v"(x));
  return r;
}

__device__ inline unsigned int cvtpk_bf16(float lo, float hi) {
  unsigned int r;
  asm("v_cvt_pk_bf16_f32 %0, %1, %2" : "=v"(r) : "v"(lo), "v"(hi));
  return r;
}

// v_permlane32_swap_b32 vdst, vsrc: vdst[32:63] <-> vsrc[0:31].
__device__ inline void pswap(unsigned int& dst, unsigned int& src) {
  asm("v_permlane32_swap_b32 %0, %1" : "+v"(dst), "+v"(src));
}

__device__ inline void gload16(void* lds, const void* g) {
  __builtin_amdgcn_global_load_lds((const __attribute__((address_space(1))) void*)g,
                                   (__attribute__((address_space(3))) void*)lds,
                                   16, 0, 0);
}

// ---------------- prep kernels ----------------

__global__ __launch_bounds__(256) void cast_f32_bf16(const float* __restrict__ src,
                                                     u16* __restrict__ dst, int n4) {
  int i = blockIdx.x * blockDim.x + threadIdx.x;
  if (i < n4) {
    float4 v = ((const float4*)src)[i];
    ushort4 o;
    o.x = f2b(v.x); o.y = f2b(v.y); o.z = f2b(v.z); o.w = f2b(v.w);
    ((ushort4*)dst)[i] = o;
  }
}

// dst[n][k] = bf16(src[k][n]); src is [K][N] f32 row-major.
__global__ __launch_bounds__(256) void transpose_cast(const float* __restrict__ src,
                                                      u16* __restrict__ dst, int K, int N) {
  __shared__ float t[32][33];
  int k0 = blockIdx.x * 32, n0 = blockIdx.y * 32;
  int tx = threadIdx.x, ty = threadIdx.y;  // 32 x 8
#pragma unroll
  for (int i = 0; i < 4; i++) t[ty + i * 8][tx] = src[(size_t)(k0 + ty + i * 8) * N + n0 + tx];
  __syncthreads();
#pragma unroll
  for (int i = 0; i < 4; i++)
    dst[(size_t)(n0 + ty + i * 8) * K + k0 + tx] = f2b(t[tx][ty + i * 8]);
}

#define QSCALE 0.1803368801f

// ---------------- GEMM1: 256x256 tile, BK=64, 8 waves, counted-vmcnt pipeline ----
// A [M][K], BT [N][K] bf16. Writes Q (scaled), Kf, Vf fragment-ready layouts.
// 2x double-buffered LDS (128 KB). Per K-tile: 4 phases, each = one C-quadrant
// (16 MFMA) + stage of one half-tile of the NEXT K-tile into the other buffer.
// Waits are counted vmcnt(4) at phases 0/1/2 (forces exactly the half-tile that
// phase needs); never vmcnt(0) in the main loop (T3+T4). setprio around MFMA (T5).
// LDS XOR-swizzle both-sides (T2, rule #21): linear gload_lds dest, pre-swizzled
// global source, swizzled ds_read: byte ^= ((row&7)<<4).
__global__ __launch_bounds__(512, 2) void gemm256_qkv(
    const u16* __restrict__ A, const u16* __restrict__ BT, const float* __restrict__ bias,
    u16* __restrict__ oQ, u16* __restrict__ oK, u16* __restrict__ oVf) {
  __shared__ __align__(16) u16 As[2][256 * 64];
  __shared__ __align__(16) u16 Bs[2][256 * 64];
  const int K = 1024, NT = 16;
  int tid = threadIdx.x;
  int wv = tid >> 6, lane = tid & 63, lr = lane & 15, lg = lane >> 4;
  int wm = wv >> 2, wn = wv & 3;
  int bx = blockIdx.x % 12, by = blockIdx.x / 12;
  int m0 = by * 256, n0 = bx * 256;
  const int swz = (lr & 7) << 4;

  f32x4 acc[8][4] = {};

  // stage half h (rows h*128..h*128+127) of tile kt into buffer buf (2 gloads)
  auto stageA = [&](int buf, int kt, int h) {
#pragma unroll
    for (int g = 0; g < 2; g++) {
      int li = g * 512 + tid;
      int row = (li >> 3) + h * 128;
      int cb = ((li & 7) * 16) ^ ((row & 7) << 4);
      gload16((char*)&As[buf][0] + h * 16384 + g * 8192 + wv * 1024,
              (const char*)(A + (size_t)(m0 + row) * K + kt * 64) + cb);
    }
  };
  auto stageB = [&](int buf, int kt, int h) {
#pragma unroll
    for (int g = 0; g < 2; g++) {
      int li = g * 512 + tid;
      int row = (li >> 3) + h * 128;
      int cb = ((li & 7) * 16) ^ ((row & 7) << 4);
      gload16((char*)&Bs[buf][0] + h * 16384 + g * 8192 + wv * 1024,
              (const char*)(BT + (size_t)(n0 + row) * K + kt * 64) + cb);
    }
  };

  // prologue: stage tile 0 into buf 0 (order A0, B0, A1, B1 = consumption order)
  stageA(0, 0, 0);
  stageB(0, 0, 0);
  stageA(0, 0, 1);
  stageB(0, 0, 1);

  for (int t = 0; t < NT; ++t) {
    const int buf = t & 1;
    const bool last = (t == NT - 1);
#pragma unroll
    for (int p = 0; p < 4; p++) {
      const int Mq = p & 1, Nq = p >> 1;  // quadrant order (M0,N0)(M1,N0)(M0,N1)(M1,N1)
      // ---- counted wait + barrier (forces the half-tiles this phase first needs)
      if (last) {
        if (p == 0) asm volatile("s_waitcnt vmcnt(0)" ::: "memory");
      } else if (p < 3) {
        asm volatile("s_waitcnt vmcnt(4)" ::: "memory");
      }
      __builtin_amdgcn_s_barrier();
      // ---- ds_read register subtile (8 A + 4 B b128 reads, swizzled)
      bf16x8 a[4][2], b[2][2];
#pragma unroll
      for (int ii = 0; ii < 4; ii++) {
        int row = wm * 16 + ii * 32 + Mq * 128 + lr;
#pragma unroll
        for (int kk = 0; kk < 2; kk++)
          a[ii][kk] = *(const bf16x8*)((const char*)&As[buf][0] + row * 128 +
                                       ((kk * 64 + lg * 16) ^ swz));
      }
#pragma unroll
      for (int jj2 = 0; jj2 < 2; jj2++) {
        int row = wn * 16 + jj2 * 64 + Nq * 128 + lr;
#pragma unroll
        for (int kk = 0; kk < 2; kk++)
          b[jj2][kk] = *(const bf16x8*)((const char*)&Bs[buf][0] + row * 128 +
                                        ((kk * 64 + lg * 16) ^ swz));
      }
      // ---- stage one half-tile of tile t+1 into the other buffer
      if (!last) {
        if (p == 0) stageA(buf ^ 1, t + 1, 0);
        else if (p == 1) stageB(buf ^ 1, t + 1, 0);
        else if (p == 2) stageA(buf ^ 1, t + 1, 1);
        else stageB(buf ^ 1, t + 1, 1);
      }
      // ---- MFMA cluster (16)
      __builtin_amdgcn_s_setprio(1);
#pragma unroll
      for (int ii = 0; ii < 4; ii++)
#pragma unroll
        for (int jj2 = 0; jj2 < 2; jj2++)
#pragma unroll
          for (int kk = 0; kk < 2; kk++)
            acc[Mq * 4 + ii][Nq * 2 + jj2] =
                MFMA_BF16(a[ii][kk], b[jj2][kk], acc[Mq * 4 + ii][Nq * 2 + jj2]);
      __builtin_amdgcn_s_setprio(0);
    }
  }

  // ---- epilogue: QKV split + scatter to Q / Kf / Vf
#pragma unroll
  for (int i = 0; i < 8; i++) {
#pragma unroll
    for (int j = 0; j < 4; j++) {
#pragma unroll
      for (int jj = 0; jj < 4; jj++) {
        int row = m0 + wm * 16 + (i & 3) * 32 + (i >> 2) * 128 + lg * 4 + jj;
        int col = n0 + wn * 16 + (j & 1) * 64 + (j >> 1) * 128 + lr;
        float v = acc[i][j][jj] + bias[col];
        int bb = row >> 11, s = row & 2047;
        int tile = s >> 6, key = s & 63;
        if (col < 1024) {
          oQ[((size_t)((bb * 16 + (col >> 6)) * 2048 + s)) * 64 + (col & 63)] = f2b(v * QSCALE);
        } else if (col < 2048) {
          int c = col - 1024;
          int hh = c >> 6, d = c & 63;
          int jf = ((key >> 5) << 2) + (d >> 4);
          int ln = (((d >> 3) & 1) << 5) | (key & 31);
          oK[(size_t)(bb * 16 + hh) * 131072 + tile * 4096 + jf * 512 + ln * 8 + (d & 7)] =
              f2b(v);
        } else {
          int c = col - 2048;
          int hh = c >> 6, d = c & 63;
          int jf = ((d >> 5) << 2) + (key >> 4);
          int ln = (((key >> 3) & 1) << 5) | (d & 31);
          oVf[(size_t)(bb * 16 + hh) * 131072 + tile * 4096 + jf * 512 + ln * 8 + (key & 7)] =
              f2b(v);
        }
      }
    }
  }
}

// ---------------- GEMM2 (128x128 tile, BK=64, T2 XOR-swizzled LDS) ----------------
__global__ __launch_bounds__(256) void gemm_bt_f32(
    const u16* __restrict__ A, const u16* __restrict__ BT, const float* __restrict__ bias,
    float* __restrict__ oF, int M, int N, int K, int nbx) {
  __shared__ __align__(16) u16 As[128 * 64];
  __shared__ __align__(16) u16 Bs[128 * 64];
  int tid = threadIdx.x;
  int wv = tid >> 6, lane = tid & 63, lr = lane & 15, lg = lane >> 4;
  int bx = blockIdx.x % nbx, by = blockIdx.x / nbx;
  int m0 = by * 128, n0 = bx * 128;
  int wr = (wv >> 1) * 64, wc = (wv & 1) * 64;

  f32x4 acc[4][4] = {};

  for (int k0 = 0; k0 < K; k0 += 64) {
#pragma unroll
    for (int j = 0; j < 4; j++) {
      int li = j * 256 + tid;
      int row = li >> 3;
      int cb = ((li & 7) * 16) ^ ((row & 7) << 4);
      gload16((char*)As + j * 4096 + wv * 1024,
              (const char*)(A + (size_t)(m0 + row) * K + k0) + cb);
      gload16((char*)Bs + j * 4096 + wv * 1024,
              (const char*)(BT + (size_t)(n0 + row) * K + k0) + cb);
    }
    __syncthreads();
#pragma unroll
    for (int kk = 0; kk < 2; kk++) {
      bf16x8 a[4], b[4];
#pragma unroll
      for (int i = 0; i < 4; i++) {
        int row = wr + i * 16 + lr;
        a[i] = *(const bf16x8*)((const char*)As + row * 128 +
                                ((kk * 64 + lg * 16) ^ ((row & 7) << 4)));
      }
#pragma unroll
      for (int j = 0; j < 4; j++) {
        int row = wc + j * 16 + lr;
        b[j] = *(const bf16x8*)((const char*)Bs + row * 128 +
                                ((kk * 64 + lg * 16) ^ ((row & 7) << 4)));
      }
#pragma unroll
      for (int i = 0; i < 4; i++)
#pragma unroll
        for (int j = 0; j < 4; j++) acc[i][j] = MFMA_BF16(a[i], b[j], acc[i][j]);
    }
    __syncthreads();
  }

#pragma unroll
  for (int i = 0; i < 4; i++)
#pragma unroll
    for (int j = 0; j < 4; j++)
#pragma unroll
      for (int jj = 0; jj < 4; jj++) {
        int row = m0 + wr + i * 16 + lg * 4 + jj;
        int col = n0 + wc + j * 16 + lr;
        oF[(size_t)row * N + col] = acc[i][j][jj] + bias[col];
      }
}

// ---------------- flash attention (swapped 32x32, KV-split, fragment-layout KV) ----------------
#define SEQL 2048
#define FIRST_END 682
#define SECOND_END 1365
#define LOG2F16 0.6780719051f

__global__ __launch_bounds__(256) void attn_kernel(const u16* __restrict__ Qb,
                                                   const u16* __restrict__ Kf,
                                                   const u16* __restrict__ Vf,
                                                   u16* __restrict__ AO) {
  __shared__ float Ol[4][16][66];   // [wave][reg r][lane], padded
  __shared__ float Ml[4][32], Ll[4][32], Cl[4][32];

  int tid = threadIdx.x;
  int w = tid >> 6, l = tid & 63;
  int r31 = l & 31, hi = l >> 5;

  // 2048 blocks: XCD gets 4 bh x 64 tiles; big tiles (qt=63) launch first.
  int xcd = blockIdx.x & 7, slot = blockIdx.x >> 3;   // slot 0..255
  int bh = xcd * 4 + (slot >> 6);
  int qt = 63 - (slot & 63);
  int q0 = qt * 32;
  int h = bh & 15, b = bh >> 4;

  // Q fragments (B-operand of swapped QK): lane holds Q[q=r31][kb*16+hi*8 .. +7]
  const u16* Qp = Qb + ((size_t)bh * SEQL + q0 + r31) * 64 + hi * 8;
  bf16x8 qa[4];
#pragma unroll
  for (int kb = 0; kb < 4; kb++) qa[kb] = *(const bf16x8*)(Qp + kb * 16);

  const u16* Kfp = Kf + (size_t)bh * 131072;
  const u16* Vfp = Vf + (size_t)bh * 131072;

  f32x16 o0 = {}, o1 = {};   // O^T tiles: d = dt*32 + (reg&3)+8*(reg>>2)+4*hi, q = r31
  float m = -1e30f, lsum = 0.f;

  const int N = (q0 + 95) >> 6;   // total 64-key steps for this q-tile
  const bool hasb = (h < 3);

  for (int t = w; t < N; t += 4) {
    const int kv0 = t << 6;
    const bool last = (t == N - 1);
    const u16* kt = Kfp + (size_t)t * 4096;
    const u16* vt = Vfp + (size_t)t * 4096;

    // ---- QK^T (swapped): sA/sB[reg] = S^T[key][q=r31]; coalesced 1KB loads
    bf16x8 ka[4], kb2[4];
#pragma unroll
    for (int kb = 0; kb < 4; kb++) {
      ka[kb]  = *(const bf16x8*)(kt + kb * 512 + l * 8);
      kb2[kb] = *(const bf16x8*)(kt + (4 + kb) * 512 + l * 8);
    }
    f32x16 sA = {}, sB = {};
#pragma unroll
    for (int kb = 0; kb < 4; kb++) sA = MFMA32(ka[kb], qa[kb], sA);
#pragma unroll
    for (int kb = 0; kb < 4; kb++) sB = MFMA32(kb2[kb], qa[kb], sB);

    if (hasb) {
#pragma unroll
      for (int r = 0; r < 16; r++) {
        int kA = kv0 + ((r & 3) + 8 * (r >> 2) + 4 * hi);
        int kB = kA + 32;
        int rA = (kA < FIRST_END) ? 0 : (kA < SECOND_END) ? 1 : 2;
        int rB = (kB < FIRST_END) ? 0 : (kB < SECOND_END) ? 1 : 2;
        if (rA == h) sA[r] += LOG2F16;
        if (rB == h) sB[r] += LOG2F16;
      }
    }
    if (last) {
      int q = q0 + r31;
#pragma unroll
      for (int r = 0; r < 16; r++) {
        int kA = kv0 + ((r & 3) + 8 * (r >> 2) + 4 * hi);
        if (kA > q) sA[r] = -1e30f;
        if (kA + 32 > q) sB[r] = -1e30f;
      }
    }

    // ---- online softmax (lane-local row, one cross-lane exchange)
#define MAX4(v, i) fmaxf(fmaxf(v[i], v[i + 1]), fmaxf(v[i + 2], v[i + 3]))
    float mA = fmaxf(fmaxf(MAX4(sA, 0), MAX4(sA, 4)), fmaxf(MAX4(sA, 8), MAX4(sA, 12)));
    float mB = fmaxf(fmaxf(MAX4(sB, 0), MAX4(sB, 4)), fmaxf(MAX4(sB, 8), MAX4(sB, 12)));
    float mx = fmaxf(mA, mB);
    mx = fmaxf(mx, __shfl_xor(mx, 32));
    float mn = fmaxf(m, mx);
    float corr = exp2_fast(m - mn);
    m = mn;

    unsigned int wA[8], wB[8];
    float s0 = 0.f, s1 = 0.f;
#pragma unroll
    for (int i = 0; i < 8; i++) {
      float pa0 = exp2_fast(sA[2 * i] - mn), pa1 = exp2_fast(sA[2 * i + 1] - mn);
      float pb0 = exp2_fast(sB[2 * i] - mn), pb1 = exp2_fast(sB[2 * i + 1] - mn);
      s0 += pa0 + pa1;
      s1 += pb0 + pb1;
      wA[i] = cvtpk_bf16(pa0, pa1);
      wB[i] = cvtpk_bf16(pb0, pb1);
    }
    float ssum = s0 + s1;
    ssum += __shfl_xor(ssum, 32);
    lsum = lsum * corr + ssum;
    o0 *= corr;
    o1 *= corr;

    // ---- P^T B-fragments via permlane32_swap
    pswap(wA[0], wA[2]); pswap(wA[1], wA[3]);
    pswap(wA[4], wA[6]); pswap(wA[5], wA[7]);
    pswap(wB[0], wB[2]); pswap(wB[1], wB[3]);
    pswap(wB[4], wB[6]); pswap(wB[5], wB[7]);

    bf16x8 pb[4];
    pb[0] = __builtin_bit_cast(bf16x8, (u32x4){wA[0], wA[1], wA[2], wA[3]});
    pb[1] = __builtin_bit_cast(bf16x8, (u32x4){wA[4], wA[5], wA[6], wA[7]});
    pb[2] = __builtin_bit_cast(bf16x8, (u32x4){wB[0], wB[1], wB[2], wB[3]});
    pb[3] = __builtin_bit_cast(bf16x8, (u32x4){wB[4], wB[5], wB[6], wB[7]});

    // ---- PV (swapped): O^T += V^T * P^T; coalesced 1KB loads
#pragma unroll
    for (int c = 0; c < 4; c++) {
      bf16x8 va0 = *(const bf16x8*)(vt + c * 512 + l * 8);
      bf16x8 va1 = *(const bf16x8*)(vt + (4 + c) * 512 + l * 8);
      o0 = MFMA32(va0, pb[c], o0);
      o1 = MFMA32(va1, pb[c], o1);
    }
  }

  // ---- merge partials across the 4 waves (2 passes over d-halves) ----
  Ml[w][r31] = m;
  Ll[w][r31] = lsum;
#pragma unroll
  for (int r = 0; r < 16; r++) Ol[w][r][l] = o0[r];
  __syncthreads();

  if (tid < 128) {
    int w2 = tid >> 5, q = tid & 31;
    float m0 = Ml[0][q], m1 = Ml[1][q], m2 = Ml[2][q], m3 = Ml[3][q];
    float ms = fmaxf(fmaxf(m0, m1), fmaxf(m2, m3));
    float e0 = exp2_fast(m0 - ms), e1 = exp2_fast(m1 - ms);
    float e2 = exp2_fast(m2 - ms), e3 = exp2_fast(m3 - ms);
    float ls = Ll[0][q] * e0 + Ll[1][q] * e1 + Ll[2][q] * e2 + Ll[3][q] * e3;
    float ei = (w2 == 0) ? e0 : (w2 == 1) ? e1 : (w2 == 2) ? e2 : e3;
    Cl[w2][q] = ei / ls;
  }
  __syncthreads();

  int mq = tid >> 3, md = (tid & 7) * 4;
  float c0 = Cl[0][mq], c1 = Cl[1][mq], c2 = Cl[2][mq], c3 = Cl[3][mq];
  u16* aop = AO + ((size_t)(b * SEQL + q0 + mq)) * 1024 + h * 64;

  {
    u16 ov[4];
#pragma unroll
    for (int j = 0; j < 4; j++) {
      int d = md + j;
      int h2 = (d >> 2) & 1, rr = (d & 3) + 4 * (d >> 3);
      int ll2 = mq + 32 * h2;
      ov[j] = f2b(Ol[0][rr][ll2] * c0 + Ol[1][rr][ll2] * c1 +
                  Ol[2][rr][ll2] * c2 + Ol[3][rr][ll2] * c3);
    }
    *(uint2*)(aop + md) = *(const uint2*)ov;
  }
  __syncthreads();
#pragma unroll
  for (int r = 0; r < 16; r++) Ol[w][r][l] = o1[r];
  __syncthreads();
  {
    u16 ov[4];
#pragma unroll
    for (int j = 0; j < 4; j++) {
      int d = md + j;
      int h2 = (d >> 2) & 1, rr = (d & 3) + 4 * (d >> 3);
      int ll2 = mq + 32 * h2;
      ov[j] = f2b(Ol[0][rr][ll2] * c0 + Ol[1][rr][ll2] * c1 +
                  Ol[2][rr][ll2] * c2 + Ol[3][rr][ll2] * c3);
    }
    *(uint2*)(aop + 32 + md) = *(const uint2*)ov;
  }
}

// ---------------- launch ----------------

extern "C" void kernel_launch(void* const* d_in, const int* in_sizes, int n_in,
                              void* d_out, int out_size, void* d_ws, size_t ws_size,
                              hipStream_t stream) {
  const float* hs = (const float*)d_in[0];   // [2][2048][1024]
  const float* w1 = (const float*)d_in[1];   // [1024][3072]
  const float* b1 = (const float*)d_in[2];   // [3072]
  const float* w2 = (const float*)d_in[3];   // [1024][1024]
  const float* b2 = (const float*)d_in[4];   // [1024]
  float* out = (float*)d_out;

  char* ws = (char*)d_ws;
  const size_t MB = 1u << 20;
  u16* hsb = (u16*)(ws + 0);        // 8 MB  [4096][1024] bf16
  u16* w1t = (u16*)(ws + 8 * MB);   // 6 MB  [3072][1024] bf16
  u16* w2t = (u16*)(ws + 14 * MB);  // 2 MB  [1024][1024] bf16
  u16* Qb = (u16*)(ws + 16 * MB);   // 8 MB  [32][2048][64] bf16, pre-scaled log2e/8
  u16* Kf = (u16*)(ws + 24 * MB);   // 8 MB  fragment-ready K
  u16* Vf = (u16*)(ws + 32 * MB);   // 8 MB  fragment-ready V^T
  u16* AO = hsb;                    // reuse: [4096][1024] bf16

  cast_f32_bf16<<<4096, 256, 0, stream>>>(hs, hsb, 4096 * 1024 / 4);
  dim3 tb(32, 8);
  transpose_cast<<<dim3(32, 96), tb, 0, stream>>>(w1, w1t, 1024, 3072);
  transpose_cast<<<dim3(32, 32), tb, 0, stream>>>(w2, w2t, 1024, 1024);

  // qkv = hs @ w1 + b1  -> Q, Kf, Vf (bf16); 256^2 8-phase pipeline
  gemm256_qkv<<<16 * 12, 512, 0, stream>>>(hsb, w1t, b1, Qb, Kf, Vf);
  // flash attention: one q-tile per block, KV-split across 4 waves
  attn_kernel<<<2048, 256, 0, stream>>>(Qb, Kf, Vf, AO);
  // out = AO @ w2 + b2 (f32)
  gemm_bt_f32<<<32 * 8, 256, 0, stream>>>(AO, w2t, b2, out, 4096, 1024, 1024, 8);
}